// Round 1
// baseline (4228.422 us; speedup 1.0000x reference)
//
#include <hip/hip_runtime.h>
#include <hip/hip_bf16.h>

// ---------- problem constants ----------
// B=4, H=8, W=8, M=16, C=256, NH=8, HD=32, GW=2
// scale0: [256, 256, 256]  scale1: [16, 256, 256]
#define C_DIM 256
#define ROWS0 65536           // 256 windows * 256 tokens
#define ROWS1 4096            // 16 windows * 256 tokens
#define CH_W  32              // windows per chunk (scale0)
#define CH_ROWS (CH_W * 256)  // 8192
#define NCHUNK 8

__device__ __forceinline__ float gelu_f(float x) {
    return 0.5f * x * (1.0f + erff(x * 0.70710678118654752f));
}

// ---------- posemb table: pe[s][n][c] = relu(coords[n] @ w1[s] + b1[s]) @ w2[s] ----------
// grid: 512 blocks (s*256+n), 256 threads (c)
__global__ __launch_bounds__(256) void pe_kernel(
    const float* __restrict__ w1, const float* __restrict__ b1,
    const float* __restrict__ w2, float* __restrict__ pe)
{
    __shared__ float hid[512];
    int blk = blockIdx.x;
    int s = blk >> 8, n = blk & 255;
    int i = n >> 4, j = n & 15;
    float c0 = (i - 8) * 0.125f;
    float c1 = (j - 8) * 0.125f;
    int t = threadIdx.x;
    for (int hh = t; hh < 512; hh += 256) {
        float hv = c0 * w1[s * 1024 + hh] + c1 * w1[s * 1024 + 512 + hh] + b1[s * 512 + hh];
        hid[hh] = fmaxf(hv, 0.f);
    }
    __syncthreads();
    float o = 0.f;
    const float* w2p = w2 + (size_t)s * 512 * 256 + t;
    #pragma unroll 8
    for (int hh = 0; hh < 512; hh++) o += hid[hh] * w2p[hh * 256];
    pe[(size_t)s * 65536 + n * 256 + t] = o;
}

// ---------- x0 = scale0 + pe0 ----------
__global__ __launch_bounds__(256) void add_pe0_kernel(
    const float* __restrict__ s0, const float* __restrict__ pe, float* __restrict__ out)
{
    int row = blockIdx.x, c = threadIdx.x;
    out[(size_t)row * 256 + c] = s0[(size_t)row * 256 + c] + pe[(row & 255) * 256 + c];
}

// ---------- x1 = scale1 + pe1 + maxpool(x0) ----------
// grid: 4096 blocks (w1*256+n1), 256 threads (c)
__global__ __launch_bounds__(256) void pool_kernel(
    const float* __restrict__ x0, const float* __restrict__ s1,
    const float* __restrict__ pe1, float* __restrict__ x1out)
{
    int w1 = blockIdx.x >> 8, n1 = blockIdx.x & 255, c = threadIdx.x;
    int b = w1 >> 2, wy = (w1 >> 1) & 1, wx = w1 & 1;
    int ty = n1 >> 4, tx = n1 & 15;
    int gy = wy * 16 + ty, gx = wx * 16 + tx;
    int h = gy >> 2, r1 = gy & 3, w = gx >> 2, r2 = gx & 3;
    int fw = (b * 8 + h) * 8 + w;
    const float* base = x0 + ((size_t)fw * 256 + r1 * 64 + r2 * 4) * 256 + c;
    float mv = -1e30f;
    #pragma unroll
    for (int p1 = 0; p1 < 4; p1++)
        #pragma unroll
        for (int p2 = 0; p2 < 4; p2++)
            mv = fmaxf(mv, base[(p1 * 16 + p2) * 256]);
    size_t oidx = ((size_t)w1 * 256 + n1) * 256 + c;
    x1out[oidx] = s1[oidx] + pe1[n1 * 256 + c] + mv;
}

// ---------- LayerNorm: one row per block ----------
__global__ __launch_bounds__(256) void ln_kernel(
    const float* __restrict__ X, const float* __restrict__ g,
    const float* __restrict__ b, float* __restrict__ Y)
{
    __shared__ float smr[4];
    int row = blockIdx.x, t = threadIdx.x;
    float x = X[(size_t)row * 256 + t];
    float v = x;
    for (int o = 32; o; o >>= 1) v += __shfl_down(v, o);
    if ((t & 63) == 0) smr[t >> 6] = v;
    __syncthreads();
    float mean = (smr[0] + smr[1] + smr[2] + smr[3]) * (1.0f / 256.0f);
    __syncthreads();
    float d = x - mean;
    float vv = d * d;
    for (int o = 32; o; o >>= 1) vv += __shfl_down(vv, o);
    if ((t & 63) == 0) smr[t >> 6] = vv;
    __syncthreads();
    float var = (smr[0] + smr[1] + smr[2] + smr[3]) * (1.0f / 256.0f);
    float inv = 1.0f / sqrtf(var + 1e-5f);
    Y[(size_t)row * 256 + t] = d * inv * g[t] + b[t];
}

// ---------- generic fp32 GEMM: Y = act(X@W + bias) [+ Res] ----------
// X:[M,K] ld=K, W:[K,N] ld=ldW, Y/Res:[M,N] ld=N. M%128==0, N%128==0, K%16==0.
// block 256 threads, tile 128x128x16, 8x8 micro-tile (4+4 split to avoid bank conflicts)
template<int ACT, int RES>
__global__ __launch_bounds__(256) void gemm_kernel(
    const float* __restrict__ X, const float* __restrict__ W, const int ldW,
    const float* __restrict__ bias, const float* __restrict__ Res,
    float* __restrict__ Y, int M, int N, int K)
{
    __shared__ float As[16][132];
    __shared__ float Bs[16][132];
    int tid = threadIdx.x;
    int tx = tid & 15, ty = tid >> 4;
    int m0 = blockIdx.y << 7, n0 = blockIdx.x << 7;
    float acc[8][8];
    #pragma unroll
    for (int i = 0; i < 8; i++)
        #pragma unroll
        for (int j = 0; j < 8; j++) acc[i][j] = 0.f;

    for (int k0 = 0; k0 < K; k0 += 16) {
        #pragma unroll
        for (int p = 0; p < 2; p++) {
            int f = tid + (p << 8);
            int ia = f >> 2, kq = (f & 3) << 2;
            float4 va = *(const float4*)(X + (size_t)(m0 + ia) * K + k0 + kq);
            As[kq + 0][ia] = va.x; As[kq + 1][ia] = va.y;
            As[kq + 2][ia] = va.z; As[kq + 3][ia] = va.w;
            int kk = f >> 5, jq = (f & 31) << 2;
            *(float4*)&Bs[kk][jq] = *(const float4*)(W + (size_t)(k0 + kk) * ldW + n0 + jq);
        }
        __syncthreads();
        #pragma unroll
        for (int kk = 0; kk < 16; kk++) {
            float a[8], bb[8];
            *(float4*)&a[0]  = *(const float4*)&As[kk][ty << 2];
            *(float4*)&a[4]  = *(const float4*)&As[kk][64 + (ty << 2)];
            *(float4*)&bb[0] = *(const float4*)&Bs[kk][tx << 2];
            *(float4*)&bb[4] = *(const float4*)&Bs[kk][64 + (tx << 2)];
            #pragma unroll
            for (int i = 0; i < 8; i++)
                #pragma unroll
                for (int j = 0; j < 8; j++)
                    acc[i][j] += a[i] * bb[j];
        }
        __syncthreads();
    }
    #pragma unroll
    for (int i = 0; i < 8; i++) {
        int row = m0 + ((i >> 2) << 6) + (ty << 2) + (i & 3);
        #pragma unroll
        for (int j = 0; j < 8; j++) {
            int col = n0 + ((j >> 2) << 6) + (tx << 2) + (j & 3);
            float v = acc[i][j] + bias[col];
            if (ACT == 1) v = gelu_f(v);
            if (RES)      v += Res[(size_t)row * N + col];
            Y[(size_t)row * N + col] = v;
        }
    }
}

// ---------- self-attention: one (window, head) per block; online softmax ----------
// qkv: [nw*256, 768] (q|k|v), out: [nw*256, 256]
__global__ __launch_bounds__(256) void attn_kernel(
    const float* __restrict__ qkv, float* __restrict__ out)
{
    __shared__ float kt[64][32];
    __shared__ float vt[64][32];
    int n = threadIdx.x;
    int win = blockIdx.x, h = blockIdx.y;
    const float* qp = qkv + ((size_t)(win * 256 + n)) * 768 + h * 32;
    float q[32];
    #pragma unroll
    for (int d = 0; d < 32; d += 4) *(float4*)&q[d] = *(const float4*)&qp[d];
    float acc[32];
    #pragma unroll
    for (int d = 0; d < 32; d++) acc[d] = 0.f;
    float mrun = -1e30f, l = 0.f;

    for (int k0 = 0; k0 < 256; k0 += 64) {
        __syncthreads();
        int r = n >> 2, cq = (n & 3) * 8;
        const float* kb = qkv + ((size_t)(win * 256 + k0 + r)) * 768 + 256 + h * 32 + cq;
        *(float4*)&kt[r][cq]     = *(const float4*)kb;
        *(float4*)&kt[r][cq + 4] = *(const float4*)(kb + 4);
        const float* vb = kb + 256;
        *(float4*)&vt[r][cq]     = *(const float4*)vb;
        *(float4*)&vt[r][cq + 4] = *(const float4*)(vb + 4);
        __syncthreads();
        for (int mk = 0; mk < 64; mk++) {
            float s = 0.f;
            #pragma unroll
            for (int d = 0; d < 32; d++) s += q[d] * kt[mk][d];
            s *= 0.17677669529663687f;
            float nm = fmaxf(mrun, s);
            float sc = expf(mrun - nm);
            float p  = expf(s - nm);
            l = l * sc + p;
            #pragma unroll
            for (int d = 0; d < 32; d++) acc[d] = acc[d] * sc + p * vt[mk][d];
            mrun = nm;
        }
    }
    float inv = 1.0f / l;
    float* op = out + ((size_t)(win * 256 + n)) * 256 + h * 32;
    #pragma unroll
    for (int d = 0; d < 32; d++) op[d] = acc[d] * inv;
}

// ---------- one2one cross-attention (per 16-token group) ----------
// Qb: [4096,256], KV: [8192,512] (k|v) for one chunk of 32 fine windows, Ob: [4096,256]
__global__ __launch_bounds__(128) void cross_attn_kernel(
    const float* __restrict__ Qb, const float* __restrict__ KV,
    float* __restrict__ Ob, int fw0)
{
    __shared__ float att_s[8][16];
    int t = threadIdx.x;
    int lw = blockIdx.x >> 4;
    int sub = blockIdx.x & 15;
    int r1 = sub >> 2, r2 = sub & 3;
    int gi = (fw0 + lw) * 16 + sub;
    int h = t >> 4, m = t & 15;
    int p1 = m >> 2, p2 = m & 3;
    int lr = lw * 256 + r1 * 64 + p1 * 16 + r2 * 4 + p2;
    const float* qp = Qb + (size_t)gi * 256 + h * 32;
    const float* kp = KV + (size_t)lr * 512 + h * 32;
    float sc = 0.f;
    #pragma unroll
    for (int d = 0; d < 32; d++) sc += qp[d] * kp[d];
    sc *= 0.17677669529663687f;
    float mx = sc;
    for (int o = 8; o; o >>= 1) mx = fmaxf(mx, __shfl_xor(mx, o));
    float e = expf(sc - mx);
    float ssum = e;
    for (int o = 8; o; o >>= 1) ssum += __shfl_xor(ssum, o);
    att_s[h][m] = e / ssum;
    __syncthreads();
    int dg = t & 15;
    int d0 = dg * 2;
    float o0 = 0.f, o1 = 0.f;
    #pragma unroll
    for (int mm = 0; mm < 16; mm++) {
        int pp1 = mm >> 2, pp2 = mm & 3;
        int lrr = lw * 256 + r1 * 64 + pp1 * 16 + r2 * 4 + pp2;
        const float* vp = KV + (size_t)lrr * 512 + 256 + h * 32;
        float a = att_s[h][mm];
        o0 += a * vp[d0];
        o1 += a * vp[d0 + 1];
    }
    Ob[(size_t)gi * 256 + h * 32 + d0]     = o0;
    Ob[(size_t)gi * 256 + h * 32 + d0 + 1] = o1;
}

// ---------- gather/scatter global tokens between o1 window layout and group order ----------
__global__ __launch_bounds__(256) void gather_g_kernel(
    const float* __restrict__ o1, float* __restrict__ G)
{
    int gi = blockIdx.x, c = threadIdx.x;
    int b = gi >> 10, rem = gi & 1023;
    int h = rem >> 7, w = (rem >> 4) & 7, r1 = (rem >> 2) & 3, r2 = rem & 3;
    int gy = h * 4 + r1, gx = w * 4 + r2;
    int w1 = (b * 2 + (gy >> 4)) * 2 + (gx >> 4);
    int n1 = (gy & 15) * 16 + (gx & 15);
    G[(size_t)gi * 256 + c] = o1[((size_t)w1 * 256 + n1) * 256 + c];
}

__global__ __launch_bounds__(256) void scatter_g_kernel(
    const float* __restrict__ G, float* __restrict__ o1)
{
    int gi = blockIdx.x, c = threadIdx.x;
    int b = gi >> 10, rem = gi & 1023;
    int h = rem >> 7, w = (rem >> 4) & 7, r1 = (rem >> 2) & 3, r2 = rem & 3;
    int gy = h * 4 + r1, gx = w * 4 + r2;
    int w1 = (b * 2 + (gy >> 4)) * 2 + (gx >> 4);
    int n1 = (gy & 15) * 16 + (gx & 15);
    o1[((size_t)w1 * 256 + n1) * 256 + c] = G[(size_t)gi * 256 + c];
}

// ---------- host ----------
extern "C" void kernel_launch(void* const* d_in, const int* in_sizes, int n_in,
                              void* d_out, int out_size, void* d_ws, size_t ws_size,
                              hipStream_t stream)
{
    const float* scale0 = (const float*)d_in[0];
    const float* scale1 = (const float*)d_in[1];
    const float* pe_w1  = (const float*)d_in[2];
    const float* pe_b1  = (const float*)d_in[3];
    const float* pe_w2  = (const float*)d_in[4];
    const float* ln1_g  = (const float*)d_in[5];
    const float* ln1_b  = (const float*)d_in[6];
    const float* wqkv   = (const float*)d_in[7];
    const float* bqkv   = (const float*)d_in[8];
    const float* wo     = (const float*)d_in[9];
    const float* bo     = (const float*)d_in[10];
    const float* ln2_g  = (const float*)d_in[11];
    const float* ln2_b  = (const float*)d_in[12];
    const float* mw1    = (const float*)d_in[13];
    const float* mb1    = (const float*)d_in[14];
    const float* mw2    = (const float*)d_in[15];
    const float* mb2    = (const float*)d_in[16];
    float* out = (float*)d_out;
    float* ws  = (float*)d_ws;

    // workspace arena (floats)
    float* PE     = ws;                         // 2*65536
    float* G      = PE + 131072;                // 4096*256
    float* Q      = G  + 1048576;               // 4096*256
    float* OX     = Q  + 1048576;               // 4096*256
    float* bufH   = OX + 1048576;               // 8192*256
    float* bufBig = bufH + 2097152;             // 8192*1024
    float* bufO   = bufBig + 8388608;           // 8192*256
    // total: 15,859,712 floats = ~60.5 MB

    auto gemmL = [&](const float* X, const float* Wp, int ldW, const float* bias,
                     const float* Res, float* Y, int M, int N, int K, int act) {
        dim3 g(N >> 7, M >> 7);
        if (act)      gemm_kernel<1, 0><<<g, 256, 0, stream>>>(X, Wp, ldW, bias, nullptr, Y, M, N, K);
        else if (Res) gemm_kernel<0, 1><<<g, 256, 0, stream>>>(X, Wp, ldW, bias, Res, Y, M, N, K);
        else          gemm_kernel<0, 0><<<g, 256, 0, stream>>>(X, Wp, ldW, bias, nullptr, Y, M, N, K);
    };

    auto sattn = [&](float* x, int Mrows, int nw, int s) {
        ln_kernel<<<Mrows, 256, 0, stream>>>(x, ln1_g + s * 256, ln1_b + s * 256, bufH);
        gemmL(bufH, wqkv + (size_t)s * 196608, 768, bqkv + s * 768, nullptr, bufBig, Mrows, 768, 256, 0);
        attn_kernel<<<dim3(nw, 8), 256, 0, stream>>>(bufBig, bufO);
        gemmL(bufO, wo + (size_t)s * 65536, 256, bo + s * 256, x, x, Mrows, 256, 256, 0);
        ln_kernel<<<Mrows, 256, 0, stream>>>(x, ln2_g + s * 256, ln2_b + s * 256, bufH);
        gemmL(bufH, mw1 + (size_t)s * 262144, 1024, mb1 + s * 1024, nullptr, bufBig, Mrows, 1024, 256, 1);
        gemmL(bufBig, mw2 + (size_t)s * 262144, 256, mb2 + s * 256, x, x, Mrows, 256, 1024, 0);
    };

    float* o1sec = out + (size_t)ROWS0 * 256;

    // 1) posemb tables
    pe_kernel<<<512, 256, 0, stream>>>(pe_w1, pe_b1, pe_w2, PE);
    // 2) x0 = scale0 + pe0  (into d_out o0 section, updated in place afterwards)
    add_pe0_kernel<<<ROWS0, 256, 0, stream>>>(scale0, PE, out);
    // 3) x1 = scale1 + pe1 + maxpool(x0)
    pool_kernel<<<ROWS1, 256, 0, stream>>>(out, scale1, PE + 65536, o1sec);
    // 4) self-attention blocks (independent; coarse then fine)
    sattn(o1sec, ROWS1, 16, 1);
    for (int c = 0; c < NCHUNK; c++)
        sattn(out + (size_t)c * CH_ROWS * 256, CH_ROWS, CH_W, 0);

    // 5) one2one cross-attention
    gather_g_kernel<<<4096, 256, 0, stream>>>(o1sec, G);
    ln_kernel<<<4096, 256, 0, stream>>>(G, ln1_g + 256, ln1_b + 256, bufH);
    gemmL(bufH, wqkv + 196608, 768, bqkv + 768, nullptr, Q, 4096, 256, 256, 0);
    for (int c = 0; c < NCHUNK; c++) {
        float* xchunk = out + (size_t)c * CH_ROWS * 256;
        ln_kernel<<<CH_ROWS, 256, 0, stream>>>(xchunk, ln1_g + 256, ln1_b + 256, bufH);
        gemmL(bufH, wqkv + 196608 + 256, 768, bqkv + 768 + 256, nullptr, bufBig, CH_ROWS, 512, 256, 0);
        cross_attn_kernel<<<512, 128, 0, stream>>>(Q, bufBig, OX, c * CH_W);
    }
    gemmL(OX, wo + 65536, 256, bo + 256, G, G, 4096, 256, 256, 0);
    ln_kernel<<<4096, 256, 0, stream>>>(G, ln2_g + 256, ln2_b + 256, bufH);
    gemmL(bufH, mw1 + 262144, 1024, mb1 + 1024, nullptr, bufBig, 4096, 1024, 256, 1);
    gemmL(bufBig, mw2 + 262144, 256, mb2 + 256, G, G, 4096, 256, 1024, 0);
    // 6) scatter updated global tokens back to o1 window layout
    scatter_g_kernel<<<4096, 256, 0, stream>>>(G, o1sec);
}

// Round 2
// 1392.717 us; speedup vs baseline: 3.0361x; 3.0361x over previous
//
#include <hip/hip_runtime.h>
#include <hip/hip_bf16.h>
#include <hip/hip_fp16.h>

// B=4, H=8, W=8, M=16, C=256, NH=8, HD=32, GW=2
#define ROWS0 65536
#define ROWS1 4096

typedef _Float16 half8 __attribute__((ext_vector_type(8)));
typedef float floatx4 __attribute__((ext_vector_type(4)));

#define LDSP(p) ((__attribute__((address_space(3))) void*)(p))
#define GLBP(p) ((const __attribute__((address_space(1))) void*)(p))

__device__ __forceinline__ float gelu_f(float x) {
    return 0.5f * x * (1.0f + erff(x * 0.70710678118654752f));
}

// ---------- posemb table ----------
__global__ __launch_bounds__(256) void pe_kernel(
    const float* __restrict__ w1, const float* __restrict__ b1,
    const float* __restrict__ w2, float* __restrict__ pe)
{
    __shared__ float hid[512];
    int blk = blockIdx.x;
    int s = blk >> 8, n = blk & 255;
    int i = n >> 4, j = n & 15;
    float c0 = (i - 8) * 0.125f;
    float c1 = (j - 8) * 0.125f;
    int t = threadIdx.x;
    for (int hh = t; hh < 512; hh += 256) {
        float hv = c0 * w1[s * 1024 + hh] + c1 * w1[s * 1024 + 512 + hh] + b1[s * 512 + hh];
        hid[hh] = fmaxf(hv, 0.f);
    }
    __syncthreads();
    float o = 0.f;
    const float* w2p = w2 + (size_t)s * 512 * 256 + t;
    #pragma unroll 8
    for (int hh = 0; hh < 512; hh++) o += hid[hh] * w2p[hh * 256];
    pe[(size_t)s * 65536 + n * 256 + t] = o;
}

__global__ __launch_bounds__(256) void add_pe0_kernel(
    const float* __restrict__ s0, const float* __restrict__ pe, float* __restrict__ out)
{
    int row = blockIdx.x, c = threadIdx.x;
    out[(size_t)row * 256 + c] = s0[(size_t)row * 256 + c] + pe[(row & 255) * 256 + c];
}

__global__ __launch_bounds__(256) void pool_kernel(
    const float* __restrict__ x0, const float* __restrict__ s1,
    const float* __restrict__ pe1, float* __restrict__ x1out)
{
    int w1 = blockIdx.x >> 8, n1 = blockIdx.x & 255, c = threadIdx.x;
    int b = w1 >> 2, wy = (w1 >> 1) & 1, wx = w1 & 1;
    int ty = n1 >> 4, tx = n1 & 15;
    int gy = wy * 16 + ty, gx = wx * 16 + tx;
    int h = gy >> 2, r1 = gy & 3, w = gx >> 2, r2 = gx & 3;
    int fw = (b * 8 + h) * 8 + w;
    const float* base = x0 + ((size_t)fw * 256 + r1 * 64 + r2 * 4) * 256 + c;
    float mv = -1e30f;
    #pragma unroll
    for (int p1 = 0; p1 < 4; p1++)
        #pragma unroll
        for (int p2 = 0; p2 < 4; p2++)
            mv = fmaxf(mv, base[(p1 * 16 + p2) * 256]);
    size_t oidx = ((size_t)w1 * 256 + n1) * 256 + c;
    x1out[oidx] = s1[oidx] + pe1[n1 * 256 + c] + mv;
}

// ---------- LayerNorm -> fp16 ----------
__global__ __launch_bounds__(256) void ln16_kernel(
    const float* __restrict__ X, const float* __restrict__ g,
    const float* __restrict__ b, _Float16* __restrict__ Y)
{
    __shared__ float smr[4];
    int row = blockIdx.x, t = threadIdx.x;
    float x = X[(size_t)row * 256 + t];
    float v = x;
    for (int o = 32; o; o >>= 1) v += __shfl_down(v, o);
    if ((t & 63) == 0) smr[t >> 6] = v;
    __syncthreads();
    float mean = (smr[0] + smr[1] + smr[2] + smr[3]) * (1.0f / 256.0f);
    __syncthreads();
    float d = x - mean;
    float vv = d * d;
    for (int o = 32; o; o >>= 1) vv += __shfl_down(vv, o);
    if ((t & 63) == 0) smr[t >> 6] = vv;
    __syncthreads();
    float var = (smr[0] + smr[1] + smr[2] + smr[3]) * (1.0f / 256.0f);
    float inv = 1.0f / sqrtf(var + 1e-5f);
    Y[(size_t)row * 256 + t] = (_Float16)(d * inv * g[t] + b[t]);
}

// ---------- weight transpose fp32[K,N] -> fp16[N,K] ----------
__global__ __launch_bounds__(256) void transposeW_kernel(
    const float* __restrict__ src, _Float16* __restrict__ dst, int K, int N)
{
    __shared__ float t[32][33];
    int k0 = blockIdx.y * 32, n0 = blockIdx.x * 32;
    int tx = threadIdx.x & 31, ty = threadIdx.x >> 5;
    for (int r = ty; r < 32; r += 8) t[r][tx] = src[(size_t)(k0 + r) * N + n0 + tx];
    __syncthreads();
    for (int r = ty; r < 32; r += 8) dst[(size_t)(n0 + r) * K + k0 + tx] = (_Float16)t[tx][r];
}

// ---------- fp16 MFMA GEMM: Y = act(A@Bw^T + bias) [+ Res] ----------
// A: fp16 [M,K] row-major; Bw: fp16 [N,K] row-major (pre-transposed weight)
// 128x128 tile, BK=64, 4 waves (2x2), 16x16x32 MFMA, XOR-swizzled LDS.
template<int ACT, int RES, int OUT16>
__global__ __launch_bounds__(256) void hgemm_kernel(
    const _Float16* __restrict__ A, const _Float16* __restrict__ Bw,
    const float* __restrict__ bias, const float* __restrict__ Res,
    void* __restrict__ Yv, int M, int N, int K)
{
    __shared__ alignas(16) _Float16 As[128 * 64];
    __shared__ alignas(16) _Float16 Bs[128 * 64];
    int tid = threadIdx.x;
    int m0 = blockIdx.y << 7, n0 = blockIdx.x << 7;
    int wave = tid >> 6, lane = tid & 63;
    int wr = wave >> 1, wc = wave & 1;
    floatx4 acc[4][4] = {};

    for (int k0 = 0; k0 < K; k0 += 64) {
        #pragma unroll
        for (int p = 0; p < 4; p++) {
            int s = tid + (p << 8);
            int row = s >> 3, phys = s & 7;
            int logc = phys ^ (row & 7);
            const _Float16* ga = A + (size_t)(m0 + row) * K + k0 + logc * 8;
            __builtin_amdgcn_global_load_lds(GLBP(ga), LDSP(&As[s * 8]), 16, 0, 0);
            const _Float16* gb = Bw + (size_t)(n0 + row) * K + k0 + logc * 8;
            __builtin_amdgcn_global_load_lds(GLBP(gb), LDSP(&Bs[s * 8]), 16, 0, 0);
        }
        __syncthreads();
        int r = lane & 15, c = lane >> 4;
        #pragma unroll
        for (int ks = 0; ks < 2; ks++) {
            half8 af[4], bf[4];
            #pragma unroll
            for (int i = 0; i < 4; i++) {
                int ra = wr * 64 + i * 16 + r;
                af[i] = *(const half8*)&As[ra * 64 + (((ks << 2) | c) ^ (ra & 7)) * 8];
                int rb = wc * 64 + i * 16 + r;
                bf[i] = *(const half8*)&Bs[rb * 64 + (((ks << 2) | c) ^ (rb & 7)) * 8];
            }
            #pragma unroll
            for (int i = 0; i < 4; i++)
                #pragma unroll
                for (int j = 0; j < 4; j++)
                    acc[i][j] = __builtin_amdgcn_mfma_f32_16x16x32_f16(af[i], bf[j], acc[i][j], 0, 0, 0);
        }
        __syncthreads();
    }

    int r = lane & 15, qrow = lane >> 4;
    #pragma unroll
    for (int j = 0; j < 4; j++) {
        int col = n0 + wc * 64 + j * 16 + r;
        float bj = bias[col];
        #pragma unroll
        for (int i = 0; i < 4; i++) {
            int rowb = m0 + wr * 64 + i * 16 + qrow * 4;
            #pragma unroll
            for (int reg = 0; reg < 4; reg++) {
                int row = rowb + reg;
                float v = acc[i][j][reg] + bj;
                if (ACT) v = gelu_f(v);
                if (RES) v += Res[(size_t)row * N + col];
                if (OUT16) ((_Float16*)Yv)[(size_t)row * N + col] = (_Float16)v;
                else       ((float*)Yv)[(size_t)row * N + col] = v;
            }
        }
    }
}

// ---------- self-attention (fp16 qkv in, fp16 out), fp32 math ----------
__global__ __launch_bounds__(256) void attn_kernel(
    const _Float16* __restrict__ qkv, _Float16* __restrict__ out)
{
    __shared__ float kt[64][36];
    __shared__ float vt[64][36];
    int n = threadIdx.x;
    int win = blockIdx.x, h = blockIdx.y;
    const half8* qp8 = (const half8*)(qkv + ((size_t)(win * 256 + n)) * 768 + h * 32);
    float q[32];
    #pragma unroll
    for (int d8 = 0; d8 < 4; d8++) {
        half8 v = qp8[d8];
        #pragma unroll
        for (int j = 0; j < 8; j++) q[d8 * 8 + j] = (float)v[j];
    }
    float acc[32];
    #pragma unroll
    for (int d = 0; d < 32; d++) acc[d] = 0.f;
    float mrun = -1e30f, l = 0.f;

    for (int k0 = 0; k0 < 256; k0 += 64) {
        __syncthreads();
        int rr = n >> 2, cq = (n & 3) * 8;
        const _Float16* kb = qkv + ((size_t)(win * 256 + k0 + rr)) * 768 + 256 + h * 32 + cq;
        half8 kv8 = *(const half8*)kb;
        half8 vv8 = *(const half8*)(kb + 256);
        #pragma unroll
        for (int j = 0; j < 8; j++) { kt[rr][cq + j] = (float)kv8[j]; vt[rr][cq + j] = (float)vv8[j]; }
        __syncthreads();
        for (int mk = 0; mk < 64; mk++) {
            float s = 0.f;
            #pragma unroll
            for (int d = 0; d < 32; d++) s += q[d] * kt[mk][d];
            s *= 0.17677669529663687f;
            float nm = fmaxf(mrun, s);
            float sc = expf(mrun - nm);
            float p  = expf(s - nm);
            l = l * sc + p;
            #pragma unroll
            for (int d = 0; d < 32; d++) acc[d] = acc[d] * sc + p * vt[mk][d];
            mrun = nm;
        }
    }
    float inv = 1.0f / l;
    _Float16* op = out + ((size_t)(win * 256 + n)) * 256 + h * 32;
    #pragma unroll
    for (int d = 0; d < 32; d++) op[d] = (_Float16)(acc[d] * inv);
}

// ---------- one2one cross-attention (fp16 in/out, fp32 math) ----------
__global__ __launch_bounds__(128) void cross_attn_kernel(
    const _Float16* __restrict__ Qb, const _Float16* __restrict__ KV,
    _Float16* __restrict__ Ob, int fw0)
{
    __shared__ float att_s[8][16];
    int t = threadIdx.x;
    int lw = blockIdx.x >> 4;
    int sub = blockIdx.x & 15;
    int r1 = sub >> 2, r2 = sub & 3;
    int gi = (fw0 + lw) * 16 + sub;
    int h = t >> 4, m = t & 15;
    int p1 = m >> 2, p2 = m & 3;
    int lr = lw * 256 + r1 * 64 + p1 * 16 + r2 * 4 + p2;
    const half8* qp = (const half8*)(Qb + (size_t)gi * 256 + h * 32);
    const half8* kp = (const half8*)(KV + (size_t)lr * 512 + h * 32);
    float sc = 0.f;
    #pragma unroll
    for (int d8 = 0; d8 < 4; d8++) {
        half8 qv = qp[d8], kv = kp[d8];
        #pragma unroll
        for (int j = 0; j < 8; j++) sc += (float)qv[j] * (float)kv[j];
    }
    sc *= 0.17677669529663687f;
    float mx = sc;
    for (int o = 8; o; o >>= 1) mx = fmaxf(mx, __shfl_xor(mx, o));
    float e = expf(sc - mx);
    float ssum = e;
    for (int o = 8; o; o >>= 1) ssum += __shfl_xor(ssum, o);
    att_s[h][m] = e / ssum;
    __syncthreads();
    int dg = t & 15;
    int d0 = dg * 2;
    float o0 = 0.f, o1 = 0.f;
    #pragma unroll
    for (int mm = 0; mm < 16; mm++) {
        int pp1 = mm >> 2, pp2 = mm & 3;
        int lrr = lw * 256 + r1 * 64 + pp1 * 16 + r2 * 4 + pp2;
        const _Float16* vp = KV + (size_t)lrr * 512 + 256 + h * 32;
        float a = att_s[h][mm];
        o0 += a * (float)vp[d0];
        o1 += a * (float)vp[d0 + 1];
    }
    Ob[(size_t)gi * 256 + h * 32 + d0]     = (_Float16)o0;
    Ob[(size_t)gi * 256 + h * 32 + d0 + 1] = (_Float16)o1;
}

// ---------- gather/scatter global tokens ----------
__global__ __launch_bounds__(256) void gather_g_kernel(
    const float* __restrict__ o1, float* __restrict__ G)
{
    int gi = blockIdx.x, c = threadIdx.x;
    int b = gi >> 10, rem = gi & 1023;
    int h = rem >> 7, w = (rem >> 4) & 7, r1 = (rem >> 2) & 3, r2 = rem & 3;
    int gy = h * 4 + r1, gx = w * 4 + r2;
    int w1 = (b * 2 + (gy >> 4)) * 2 + (gx >> 4);
    int n1 = (gy & 15) * 16 + (gx & 15);
    G[(size_t)gi * 256 + c] = o1[((size_t)w1 * 256 + n1) * 256 + c];
}

__global__ __launch_bounds__(256) void scatter_g_kernel(
    const float* __restrict__ G, float* __restrict__ o1)
{
    int gi = blockIdx.x, c = threadIdx.x;
    int b = gi >> 10, rem = gi & 1023;
    int h = rem >> 7, w = (rem >> 4) & 7, r1 = (rem >> 2) & 3, r2 = rem & 3;
    int gy = h * 4 + r1, gx = w * 4 + r2;
    int w1 = (b * 2 + (gy >> 4)) * 2 + (gx >> 4);
    int n1 = (gy & 15) * 16 + (gx & 15);
    o1[((size_t)w1 * 256 + n1) * 256 + c] = G[(size_t)gi * 256 + c];
}

// ---------- host ----------
extern "C" void kernel_launch(void* const* d_in, const int* in_sizes, int n_in,
                              void* d_out, int out_size, void* d_ws, size_t ws_size,
                              hipStream_t stream)
{
    const float* scale0 = (const float*)d_in[0];
    const float* scale1 = (const float*)d_in[1];
    const float* pe_w1  = (const float*)d_in[2];
    const float* pe_b1  = (const float*)d_in[3];
    const float* pe_w2  = (const float*)d_in[4];
    const float* ln1_g  = (const float*)d_in[5];
    const float* ln1_b  = (const float*)d_in[6];
    const float* wqkv   = (const float*)d_in[7];
    const float* bqkv   = (const float*)d_in[8];
    const float* wo     = (const float*)d_in[9];
    const float* bo     = (const float*)d_in[10];
    const float* ln2_g  = (const float*)d_in[11];
    const float* ln2_b  = (const float*)d_in[12];
    const float* mw1    = (const float*)d_in[13];
    const float* mb1    = (const float*)d_in[14];
    const float* mw2    = (const float*)d_in[15];
    const float* mb2    = (const float*)d_in[16];
    float* out = (float*)d_out;
    char* arena = (char*)d_ws;

    // fixed sections
    float*    PE     = (float*)arena;              arena += 131072 * 4;
    float*    G      = (float*)arena;              arena += (size_t)4096 * 256 * 4;
    _Float16* Q16    = (_Float16*)arena;           arena += (size_t)4096 * 256 * 2;
    _Float16* OX16   = (_Float16*)arena;           arena += (size_t)4096 * 256 * 2;
    _Float16* wqkvT  = (_Float16*)arena;           arena += (size_t)2 * 768 * 256 * 2;
    _Float16* woT    = (_Float16*)arena;           arena += (size_t)2 * 256 * 256 * 2;
    _Float16* mw1T   = (_Float16*)arena;           arena += (size_t)2 * 1024 * 256 * 2;
    _Float16* mw2T   = (_Float16*)arena;           arena += (size_t)2 * 256 * 1024 * 2;
    size_t fixed_bytes = (size_t)(arena - (char*)d_ws);

    // adaptive chunk rows: per-row = 256+768+1024+256 halves = 4608 B
    int R = 8192;
    if (fixed_bytes + (size_t)65536 * 4608 <= ws_size) R = 65536;
    else if (fixed_bytes + (size_t)32768 * 4608 <= ws_size) R = 32768;
    else if (fixed_bytes + (size_t)16384 * 4608 <= ws_size) R = 16384;
    int NC = 65536 / R;
    int CW = R / 256;

    _Float16* bufH16 = (_Float16*)arena;           arena += (size_t)R * 256 * 2;
    _Float16* qkv16  = (_Float16*)arena;           arena += (size_t)R * 768 * 2;
    _Float16* hid16  = (_Float16*)arena;           arena += (size_t)R * 1024 * 2;
    _Float16* o16    = (_Float16*)arena;

    auto hgemm = [&](const _Float16* A, const _Float16* Bw, const float* bias,
                     const float* Res, void* Y, int M, int N, int K, int act, int out16) {
        dim3 g(N >> 7, M >> 7);
        if (act)           hgemm_kernel<1, 0, 1><<<g, 256, 0, stream>>>(A, Bw, bias, nullptr, Y, M, N, K);
        else if (Res)      hgemm_kernel<0, 1, 0><<<g, 256, 0, stream>>>(A, Bw, bias, Res, Y, M, N, K);
        else               hgemm_kernel<0, 0, 1><<<g, 256, 0, stream>>>(A, Bw, bias, nullptr, Y, M, N, K);
    };

    auto sattn = [&](float* x, int Mrows, int nw, int s) {
        ln16_kernel<<<Mrows, 256, 0, stream>>>(x, ln1_g + s * 256, ln1_b + s * 256, bufH16);
        hgemm(bufH16, wqkvT + (size_t)s * 196608, bqkv + s * 768, nullptr, qkv16, Mrows, 768, 256, 0, 1);
        attn_kernel<<<dim3(nw, 8), 256, 0, stream>>>(qkv16, o16);
        hgemm(o16, woT + (size_t)s * 65536, bo + s * 256, x, x, Mrows, 256, 256, 0, 0);
        ln16_kernel<<<Mrows, 256, 0, stream>>>(x, ln2_g + s * 256, ln2_b + s * 256, bufH16);
        hgemm(bufH16, mw1T + (size_t)s * 262144, mb1 + s * 1024, nullptr, hid16, Mrows, 1024, 256, 1, 1);
        hgemm(hid16, mw2T + (size_t)s * 262144, mb2 + s * 256, x, x, Mrows, 256, 1024, 0, 0);
    };

    float* o1sec = out + (size_t)ROWS0 * 256;

    // 0) weight transposes (fp32 -> fp16 [N,K])
    transposeW_kernel<<<dim3(768 / 32, 256 / 32), 256, 0, stream>>>(wqkv, wqkvT, 256, 768);
    transposeW_kernel<<<dim3(768 / 32, 256 / 32), 256, 0, stream>>>(wqkv + 196608, wqkvT + 196608, 256, 768);
    transposeW_kernel<<<dim3(256 / 32, 256 / 32), 256, 0, stream>>>(wo, woT, 256, 256);
    transposeW_kernel<<<dim3(256 / 32, 256 / 32), 256, 0, stream>>>(wo + 65536, woT + 65536, 256, 256);
    transposeW_kernel<<<dim3(1024 / 32, 256 / 32), 256, 0, stream>>>(mw1, mw1T, 256, 1024);
    transposeW_kernel<<<dim3(1024 / 32, 256 / 32), 256, 0, stream>>>(mw1 + 262144, mw1T + 262144, 256, 1024);
    transposeW_kernel<<<dim3(256 / 32, 1024 / 32), 256, 0, stream>>>(mw2, mw2T, 1024, 256);
    transposeW_kernel<<<dim3(256 / 32, 1024 / 32), 256, 0, stream>>>(mw2 + 262144, mw2T + 262144, 1024, 256);

    // 1) posemb tables; 2) x0 = scale0 + pe0; 3) x1 = scale1 + pe1 + maxpool(x0)
    pe_kernel<<<512, 256, 0, stream>>>(pe_w1, pe_b1, pe_w2, PE);
    add_pe0_kernel<<<ROWS0, 256, 0, stream>>>(scale0, PE, out);
    pool_kernel<<<ROWS1, 256, 0, stream>>>(out, scale1, PE + 65536, o1sec);

    // 4) self-attention blocks
    sattn(o1sec, ROWS1, 16, 1);
    for (int c = 0; c < NC; c++)
        sattn(out + (size_t)c * R * 256, R, CW, 0);

    // 5) one2one cross-attention
    gather_g_kernel<<<4096, 256, 0, stream>>>(o1sec, G);
    ln16_kernel<<<4096, 256, 0, stream>>>(G, ln1_g + 256, ln1_b + 256, bufH16);
    hgemm(bufH16, wqkvT + 196608, bqkv + 768, nullptr, Q16, 4096, 256, 256, 0, 1);
    for (int c = 0; c < NC; c++) {
        float* xch = out + (size_t)c * R * 256;
        ln16_kernel<<<R, 256, 0, stream>>>(xch, ln1_g + 256, ln1_b + 256, bufH16);
        hgemm(bufH16, wqkvT + 196608 + 65536, bqkv + 768 + 256, nullptr, qkv16, R, 512, 256, 0, 1);
        cross_attn_kernel<<<CW * 16, 128, 0, stream>>>(Q16, qkv16, OX16, c * CW);
    }
    hgemm(OX16, woT + 65536, bo + 256, G, G, 4096, 256, 256, 0, 0);
    ln16_kernel<<<4096, 256, 0, stream>>>(G, ln2_g + 256, ln2_b + 256, bufH16);
    hgemm(bufH16, mw1T + 262144, mb1 + 1024, nullptr, hid16, 4096, 1024, 256, 1, 1);
    hgemm(hid16, mw2T + 262144, mb2 + 256, G, G, 4096, 256, 1024, 0, 0);
    scatter_g_kernel<<<4096, 256, 0, stream>>>(G, o1sec);
}

// Round 3
// 937.900 us; speedup vs baseline: 4.5084x; 1.4849x over previous
//
#include <hip/hip_runtime.h>
#include <hip/hip_bf16.h>
#include <hip/hip_fp16.h>

// B=4, H=8, W=8, M=16, C=256, NH=8, HD=32, GW=2
#define ROWS0 65536
#define ROWS1 4096

typedef _Float16 half8 __attribute__((ext_vector_type(8)));
typedef _Float16 half4_t __attribute__((ext_vector_type(4)));
typedef float floatx4 __attribute__((ext_vector_type(4)));

#define LDSP(p) ((__attribute__((address_space(3))) void*)(p))
#define GLBP(p) ((const __attribute__((address_space(1))) void*)(p))

__device__ __forceinline__ float gelu_f(float x) {
    return 0.5f * x * (1.0f + erff(x * 0.70710678118654752f));
}

// ---------- posemb table ----------
__global__ __launch_bounds__(256) void pe_kernel(
    const float* __restrict__ w1, const float* __restrict__ b1,
    const float* __restrict__ w2, float* __restrict__ pe)
{
    __shared__ float hid[512];
    int blk = blockIdx.x;
    int s = blk >> 8, n = blk & 255;
    int i = n >> 4, j = n & 15;
    float c0 = (i - 8) * 0.125f;
    float c1 = (j - 8) * 0.125f;
    int t = threadIdx.x;
    for (int hh = t; hh < 512; hh += 256) {
        float hv = c0 * w1[s * 1024 + hh] + c1 * w1[s * 1024 + 512 + hh] + b1[s * 512 + hh];
        hid[hh] = fmaxf(hv, 0.f);
    }
    __syncthreads();
    float o = 0.f;
    const float* w2p = w2 + (size_t)s * 512 * 256 + t;
    #pragma unroll 8
    for (int hh = 0; hh < 512; hh++) o += hid[hh] * w2p[hh * 256];
    pe[(size_t)s * 65536 + n * 256 + t] = o;
}

__global__ __launch_bounds__(256) void add_pe0_kernel(
    const float* __restrict__ s0, const float* __restrict__ pe, float* __restrict__ out)
{
    int row = blockIdx.x, c = threadIdx.x;
    out[(size_t)row * 256 + c] = s0[(size_t)row * 256 + c] + pe[(row & 255) * 256 + c];
}

__global__ __launch_bounds__(256) void pool_kernel(
    const float* __restrict__ x0, const float* __restrict__ s1,
    const float* __restrict__ pe1, float* __restrict__ x1out)
{
    int w1 = blockIdx.x >> 8, n1 = blockIdx.x & 255, c = threadIdx.x;
    int b = w1 >> 2, wy = (w1 >> 1) & 1, wx = w1 & 1;
    int ty = n1 >> 4, tx = n1 & 15;
    int gy = wy * 16 + ty, gx = wx * 16 + tx;
    int h = gy >> 2, r1 = gy & 3, w = gx >> 2, r2 = gx & 3;
    int fw = (b * 8 + h) * 8 + w;
    const float* base = x0 + ((size_t)fw * 256 + r1 * 64 + r2 * 4) * 256 + c;
    float mv = -1e30f;
    #pragma unroll
    for (int p1 = 0; p1 < 4; p1++)
        #pragma unroll
        for (int p2 = 0; p2 < 4; p2++)
            mv = fmaxf(mv, base[(p1 * 16 + p2) * 256]);
    size_t oidx = ((size_t)w1 * 256 + n1) * 256 + c;
    x1out[oidx] = s1[oidx] + pe1[n1 * 256 + c] + mv;
}

// ---------- LayerNorm -> fp16 ----------
__global__ __launch_bounds__(256) void ln16_kernel(
    const float* __restrict__ X, const float* __restrict__ g,
    const float* __restrict__ b, _Float16* __restrict__ Y)
{
    __shared__ float smr[4];
    int row = blockIdx.x, t = threadIdx.x;
    float x = X[(size_t)row * 256 + t];
    float v = x;
    for (int o = 32; o; o >>= 1) v += __shfl_down(v, o);
    if ((t & 63) == 0) smr[t >> 6] = v;
    __syncthreads();
    float mean = (smr[0] + smr[1] + smr[2] + smr[3]) * (1.0f / 256.0f);
    __syncthreads();
    float d = x - mean;
    float vv = d * d;
    for (int o = 32; o; o >>= 1) vv += __shfl_down(vv, o);
    if ((t & 63) == 0) smr[t >> 6] = vv;
    __syncthreads();
    float var = (smr[0] + smr[1] + smr[2] + smr[3]) * (1.0f / 256.0f);
    float inv = 1.0f / sqrtf(var + 1e-5f);
    Y[(size_t)row * 256 + t] = (_Float16)(d * inv * g[t] + b[t]);
}

// ---------- weight transpose fp32[K,N] -> fp16[N,K] ----------
__global__ __launch_bounds__(256) void transposeW_kernel(
    const float* __restrict__ src, _Float16* __restrict__ dst, int K, int N)
{
    __shared__ float t[32][33];
    int k0 = blockIdx.y * 32, n0 = blockIdx.x * 32;
    int tx = threadIdx.x & 31, ty = threadIdx.x >> 5;
    for (int r = ty; r < 32; r += 8) t[r][tx] = src[(size_t)(k0 + r) * N + n0 + tx];
    __syncthreads();
    for (int r = ty; r < 32; r += 8) dst[(size_t)(n0 + r) * K + k0 + tx] = (_Float16)t[tx][r];
}

// ---------- fp16 MFMA GEMM (128x128 tile, BK=64) ----------
template<int ACT, int RES, int OUT16>
__global__ __launch_bounds__(256) void hgemm_kernel(
    const _Float16* __restrict__ A, const _Float16* __restrict__ Bw,
    const float* __restrict__ bias, const float* __restrict__ Res,
    void* __restrict__ Yv, int M, int N, int K)
{
    __shared__ alignas(16) _Float16 As[128 * 64];
    __shared__ alignas(16) _Float16 Bs[128 * 64];
    int tid = threadIdx.x;
    int m0 = blockIdx.y << 7, n0 = blockIdx.x << 7;
    int wave = tid >> 6, lane = tid & 63;
    int wr = wave >> 1, wc = wave & 1;
    floatx4 acc[4][4] = {};

    for (int k0 = 0; k0 < K; k0 += 64) {
        #pragma unroll
        for (int p = 0; p < 4; p++) {
            int s = tid + (p << 8);
            int row = s >> 3, phys = s & 7;
            int logc = phys ^ (row & 7);
            const _Float16* ga = A + (size_t)(m0 + row) * K + k0 + logc * 8;
            __builtin_amdgcn_global_load_lds(GLBP(ga), LDSP(&As[s * 8]), 16, 0, 0);
            const _Float16* gb = Bw + (size_t)(n0 + row) * K + k0 + logc * 8;
            __builtin_amdgcn_global_load_lds(GLBP(gb), LDSP(&Bs[s * 8]), 16, 0, 0);
        }
        __syncthreads();
        int r = lane & 15, c = lane >> 4;
        #pragma unroll
        for (int ks = 0; ks < 2; ks++) {
            half8 af[4], bf[4];
            #pragma unroll
            for (int i = 0; i < 4; i++) {
                int ra = wr * 64 + i * 16 + r;
                af[i] = *(const half8*)&As[ra * 64 + (((ks << 2) | c) ^ (ra & 7)) * 8];
                int rb = wc * 64 + i * 16 + r;
                bf[i] = *(const half8*)&Bs[rb * 64 + (((ks << 2) | c) ^ (rb & 7)) * 8];
            }
            #pragma unroll
            for (int i = 0; i < 4; i++)
                #pragma unroll
                for (int j = 0; j < 4; j++)
                    acc[i][j] = __builtin_amdgcn_mfma_f32_16x16x32_f16(af[i], bf[j], acc[i][j], 0, 0, 0);
        }
        __syncthreads();
    }

    int r = lane & 15, qrow = lane >> 4;
    #pragma unroll
    for (int j = 0; j < 4; j++) {
        int col = n0 + wc * 64 + j * 16 + r;
        float bj = bias[col];
        #pragma unroll
        for (int i = 0; i < 4; i++) {
            int rowb = m0 + wr * 64 + i * 16 + qrow * 4;
            #pragma unroll
            for (int reg = 0; reg < 4; reg++) {
                int row = rowb + reg;
                float v = acc[i][j][reg] + bj;
                if (ACT) v = gelu_f(v);
                if (RES) v += Res[(size_t)row * N + col];
                if (OUT16) ((_Float16*)Yv)[(size_t)row * N + col] = (_Float16)v;
                else       ((float*)Yv)[(size_t)row * N + col] = v;
            }
        }
    }
}

// ---------- MFMA self-attention: one (window, head) per block, 4 waves ----------
// qkv: [nw*256, 768] fp16 (q|k|v), out: [nw*256, 256] fp16
__global__ __launch_bounds__(256) void attn_mfma_kernel(
    const _Float16* __restrict__ qkv, _Float16* __restrict__ out)
{
    __shared__ alignas(16) _Float16 Klds[8192];   // [256 tok][32 d], row-pair XOR swizzle
    __shared__ alignas(16) _Float16 Qlds[8192];   // same layout
    __shared__ alignas(16) _Float16 VT[8192];     // [32 d][256 tok], chunk XOR swizzle
    __shared__ alignas(16) _Float16 Pl[4][4096];  // per-wave P tile [16 q][256 k]

    int tid = threadIdx.x;
    int win = blockIdx.x, head = blockIdx.y;
    int w = tid >> 6, lane = tid & 63;
    int r = lane & 15, h = lane >> 4;

    // ---- stage Q, K (swizzled rows) and V transposed ----
    {
        const _Float16* base = qkv + ((size_t)(win * 256 + tid)) * 768 + head * 32;
        half8 qv[4], kv[4], vv[4];
        #pragma unroll
        for (int c = 0; c < 4; c++) {
            qv[c] = *(const half8*)(base + c * 8);
            kv[c] = *(const half8*)(base + 256 + c * 8);
            vv[c] = *(const half8*)(base + 512 + c * 8);
        }
        int rowbase = (tid >> 1) * 64;
        #pragma unroll
        for (int c = 0; c < 4; c++) {
            int phys = (((tid & 1) << 2) + c) ^ ((tid >> 1) & 7);
            *(half8*)&Qlds[rowbase + phys * 8] = qv[c];
            *(half8*)&Klds[rowbase + phys * 8] = kv[c];
        }
        #pragma unroll
        for (int d = 0; d < 32; d++)
            VT[d * 256 + (((tid >> 3) ^ (d & 7)) << 3) + (tid & 7)] = vv[d >> 3][d & 7];
    }
    __syncthreads();

    // cache V^T A-frags: vf[dc][kc2] covers d = dc*16+r, k = kc2*32 + h*8 ..+8
    half8 vf[2][8];
    #pragma unroll
    for (int dc = 0; dc < 2; dc++)
        #pragma unroll
        for (int kc2 = 0; kc2 < 8; kc2++)
            vf[dc][kc2] = *(const half8*)&VT[(dc * 16 + r) * 256 + ((((kc2 << 2) + h) ^ (r & 7)) << 3)];

    const floatx4 zf = {0.f, 0.f, 0.f, 0.f};
    int physa = (((r & 1) << 2) + h) ^ ((r >> 1) & 7);  // K/Q frag chunk (constant per lane)

    for (int g = 0; g < 4; g++) {
        int qg = (w << 2) + g;
        // B-frag: Q[qg*16 + r][h*8 ..+8]
        half8 qb = *(const half8*)&Qlds[((qg << 3) + (r >> 1)) * 64 + physa * 8];
        // scores S^T: lane holds q = qg*16+r, k = kc*16 + 4h + reg
        floatx4 s[16];
        #pragma unroll
        for (int kc = 0; kc < 16; kc++) {
            half8 ka = *(const half8*)&Klds[((kc << 3) + (r >> 1)) * 64 + physa * 8];
            s[kc] = __builtin_amdgcn_mfma_f32_16x16x32_f16(ka, qb, zf, 0, 0, 0);
        }
        // softmax over k (lane-local 64 values + reduce across the 4 h-lanes)
        float m = -1e30f;
        #pragma unroll
        for (int kc = 0; kc < 16; kc++)
            #pragma unroll
            for (int e = 0; e < 4; e++) m = fmaxf(m, s[kc][e]);
        m = fmaxf(m, __shfl_xor(m, 16));
        m = fmaxf(m, __shfl_xor(m, 32));
        float l = 0.f;
        #pragma unroll
        for (int kc = 0; kc < 16; kc++)
            #pragma unroll
            for (int e = 0; e < 4; e++) {
                float p = __expf((s[kc][e] - m) * 0.17677669529663687f);
                s[kc][e] = p;
                l += p;
            }
        l += __shfl_xor(l, 16);
        l += __shfl_xor(l, 32);
        float inv = 1.0f / l;
        // write P to per-wave LDS tile [q=r][k], swizzled
        #pragma unroll
        for (int kc = 0; kc < 16; kc++) {
            half4_t pk;
            pk[0] = (_Float16)s[kc][0]; pk[1] = (_Float16)s[kc][1];
            pk[2] = (_Float16)s[kc][2]; pk[3] = (_Float16)s[kc][3];
            *(half4_t*)&Pl[w][r * 256 + ((((kc << 1) + (h >> 1)) ^ (r & 7)) << 3) + ((h & 1) << 2)] = pk;
        }
        // PV: O^T[d][q] += VT-frag @ P-frag
        floatx4 o0 = zf, o1 = zf;
        #pragma unroll
        for (int kc2 = 0; kc2 < 8; kc2++) {
            half8 pb = *(const half8*)&Pl[w][r * 256 + ((((kc2 << 2) + h) ^ (r & 7)) << 3)];
            o0 = __builtin_amdgcn_mfma_f32_16x16x32_f16(vf[0][kc2], pb, o0, 0, 0, 0);
            o1 = __builtin_amdgcn_mfma_f32_16x16x32_f16(vf[1][kc2], pb, o1, 0, 0, 0);
        }
        // scale, bounce through LDS (reuse Pl[w]) for coalesced store
        #pragma unroll
        for (int dc = 0; dc < 2; dc++) {
            floatx4 o = dc ? o1 : o0;
            half4_t oh;
            #pragma unroll
            for (int e = 0; e < 4; e++) oh[e] = (_Float16)(o[e] * inv);
            *(half4_t*)&Pl[w][(r >> 1) * 64 + (((((r & 1) << 2) + (dc << 1) + (h >> 1)) ^ ((r >> 1) & 7)) << 3) + ((h & 1) << 2)] = oh;
        }
        int q2 = lane >> 2, c2 = lane & 3;
        half8 ov = *(const half8*)&Pl[w][(q2 >> 1) * 64 + (((((q2 & 1) << 2) + c2) ^ ((q2 >> 1) & 7)) << 3)];
        *(half8*)(out + ((size_t)(win * 256 + qg * 16 + q2)) * 256 + head * 32 + c2 * 8) = ov;
    }
}

// ---------- one2one cross-attention (fp16 in/out, fp32 math) ----------
__global__ __launch_bounds__(128) void cross_attn_kernel(
    const _Float16* __restrict__ Qb, const _Float16* __restrict__ KV,
    _Float16* __restrict__ Ob, int fw0)
{
    __shared__ float att_s[8][16];
    int t = threadIdx.x;
    int lw = blockIdx.x >> 4;
    int sub = blockIdx.x & 15;
    int r1 = sub >> 2, r2 = sub & 3;
    int gi = (fw0 + lw) * 16 + sub;
    int h = t >> 4, m = t & 15;
    int p1 = m >> 2, p2 = m & 3;
    int lr = lw * 256 + r1 * 64 + p1 * 16 + r2 * 4 + p2;
    const half8* qp = (const half8*)(Qb + (size_t)gi * 256 + h * 32);
    const half8* kp = (const half8*)(KV + (size_t)lr * 512 + h * 32);
    float sc = 0.f;
    #pragma unroll
    for (int d8 = 0; d8 < 4; d8++) {
        half8 qv = qp[d8], kv = kp[d8];
        #pragma unroll
        for (int j = 0; j < 8; j++) sc += (float)qv[j] * (float)kv[j];
    }
    sc *= 0.17677669529663687f;
    float mx = sc;
    for (int o = 8; o; o >>= 1) mx = fmaxf(mx, __shfl_xor(mx, o));
    float e = __expf(sc - mx);
    float ssum = e;
    for (int o = 8; o; o >>= 1) ssum += __shfl_xor(ssum, o);
    att_s[h][m] = e / ssum;
    __syncthreads();
    int dg = t & 15;
    int d0 = dg * 2;
    float o0 = 0.f, o1 = 0.f;
    #pragma unroll
    for (int mm = 0; mm < 16; mm++) {
        int pp1 = mm >> 2, pp2 = mm & 3;
        int lrr = lw * 256 + r1 * 64 + pp1 * 16 + r2 * 4 + pp2;
        const _Float16* vp = KV + (size_t)lrr * 512 + 256 + h * 32;
        float a = att_s[h][mm];
        o0 += a * (float)vp[d0];
        o1 += a * (float)vp[d0 + 1];
    }
    Ob[(size_t)gi * 256 + h * 32 + d0]     = (_Float16)o0;
    Ob[(size_t)gi * 256 + h * 32 + d0 + 1] = (_Float16)o1;
}

// ---------- gather/scatter global tokens ----------
__global__ __launch_bounds__(256) void gather_g_kernel(
    const float* __restrict__ o1, float* __restrict__ G)
{
    int gi = blockIdx.x, c = threadIdx.x;
    int b = gi >> 10, rem = gi & 1023;
    int h = rem >> 7, w = (rem >> 4) & 7, r1 = (rem >> 2) & 3, r2 = rem & 3;
    int gy = h * 4 + r1, gx = w * 4 + r2;
    int w1 = (b * 2 + (gy >> 4)) * 2 + (gx >> 4);
    int n1 = (gy & 15) * 16 + (gx & 15);
    G[(size_t)gi * 256 + c] = o1[((size_t)w1 * 256 + n1) * 256 + c];
}

__global__ __launch_bounds__(256) void scatter_g_kernel(
    const float* __restrict__ G, float* __restrict__ o1)
{
    int gi = blockIdx.x, c = threadIdx.x;
    int b = gi >> 10, rem = gi & 1023;
    int h = rem >> 7, w = (rem >> 4) & 7, r1 = (rem >> 2) & 3, r2 = rem & 3;
    int gy = h * 4 + r1, gx = w * 4 + r2;
    int w1 = (b * 2 + (gy >> 4)) * 2 + (gx >> 4);
    int n1 = (gy & 15) * 16 + (gx & 15);
    o1[((size_t)w1 * 256 + n1) * 256 + c] = G[(size_t)gi * 256 + c];
}

// ---------- host ----------
extern "C" void kernel_launch(void* const* d_in, const int* in_sizes, int n_in,
                              void* d_out, int out_size, void* d_ws, size_t ws_size,
                              hipStream_t stream)
{
    const float* scale0 = (const float*)d_in[0];
    const float* scale1 = (const float*)d_in[1];
    const float* pe_w1  = (const float*)d_in[2];
    const float* pe_b1  = (const float*)d_in[3];
    const float* pe_w2  = (const float*)d_in[4];
    const float* ln1_g  = (const float*)d_in[5];
    const float* ln1_b  = (const float*)d_in[6];
    const float* wqkv   = (const float*)d_in[7];
    const float* bqkv   = (const float*)d_in[8];
    const float* wo     = (const float*)d_in[9];
    const float* bo     = (const float*)d_in[10];
    const float* ln2_g  = (const float*)d_in[11];
    const float* ln2_b  = (const float*)d_in[12];
    const float* mw1    = (const float*)d_in[13];
    const float* mb1    = (const float*)d_in[14];
    const float* mw2    = (const float*)d_in[15];
    const float* mb2    = (const float*)d_in[16];
    float* out = (float*)d_out;
    char* arena = (char*)d_ws;

    float*    PE     = (float*)arena;              arena += 131072 * 4;
    float*    G      = (float*)arena;              arena += (size_t)4096 * 256 * 4;
    _Float16* Q16    = (_Float16*)arena;           arena += (size_t)4096 * 256 * 2;
    _Float16* OX16   = (_Float16*)arena;           arena += (size_t)4096 * 256 * 2;
    _Float16* wqkvT  = (_Float16*)arena;           arena += (size_t)2 * 768 * 256 * 2;
    _Float16* woT    = (_Float16*)arena;           arena += (size_t)2 * 256 * 256 * 2;
    _Float16* mw1T   = (_Float16*)arena;           arena += (size_t)2 * 1024 * 256 * 2;
    _Float16* mw2T   = (_Float16*)arena;           arena += (size_t)2 * 256 * 1024 * 2;
    size_t fixed_bytes = (size_t)(arena - (char*)d_ws);

    int R = 8192;
    if (fixed_bytes + (size_t)65536 * 4608 <= ws_size) R = 65536;
    else if (fixed_bytes + (size_t)32768 * 4608 <= ws_size) R = 32768;
    else if (fixed_bytes + (size_t)16384 * 4608 <= ws_size) R = 16384;
    int NC = 65536 / R;
    int CW = R / 256;

    _Float16* bufH16 = (_Float16*)arena;           arena += (size_t)R * 256 * 2;
    _Float16* qkv16  = (_Float16*)arena;           arena += (size_t)R * 768 * 2;
    _Float16* hid16  = (_Float16*)arena;           arena += (size_t)R * 1024 * 2;
    _Float16* o16    = (_Float16*)arena;

    auto hgemm = [&](const _Float16* A, const _Float16* Bw, const float* bias,
                     const float* Res, void* Y, int M, int N, int K, int act) {
        dim3 g(N >> 7, M >> 7);
        if (act)           hgemm_kernel<1, 0, 1><<<g, 256, 0, stream>>>(A, Bw, bias, nullptr, Y, M, N, K);
        else if (Res)      hgemm_kernel<0, 1, 0><<<g, 256, 0, stream>>>(A, Bw, bias, Res, Y, M, N, K);
        else               hgemm_kernel<0, 0, 1><<<g, 256, 0, stream>>>(A, Bw, bias, nullptr, Y, M, N, K);
    };

    auto sattn = [&](float* x, int Mrows, int nw, int s) {
        ln16_kernel<<<Mrows, 256, 0, stream>>>(x, ln1_g + s * 256, ln1_b + s * 256, bufH16);
        hgemm(bufH16, wqkvT + (size_t)s * 196608, bqkv + s * 768, nullptr, qkv16, Mrows, 768, 256, 0);
        attn_mfma_kernel<<<dim3(nw, 8), 256, 0, stream>>>(qkv16, o16);
        hgemm(o16, woT + (size_t)s * 65536, bo + s * 256, x, x, Mrows, 256, 256, 0);
        ln16_kernel<<<Mrows, 256, 0, stream>>>(x, ln2_g + s * 256, ln2_b + s * 256, bufH16);
        hgemm(bufH16, mw1T + (size_t)s * 262144, mb1 + s * 1024, nullptr, hid16, Mrows, 1024, 256, 1);
        hgemm(hid16, mw2T + (size_t)s * 262144, mb2 + s * 256, x, x, Mrows, 256, 1024, 0);
    };

    float* o1sec = out + (size_t)ROWS0 * 256;

    transposeW_kernel<<<dim3(768 / 32, 256 / 32), 256, 0, stream>>>(wqkv, wqkvT, 256, 768);
    transposeW_kernel<<<dim3(768 / 32, 256 / 32), 256, 0, stream>>>(wqkv + 196608, wqkvT + 196608, 256, 768);
    transposeW_kernel<<<dim3(256 / 32, 256 / 32), 256, 0, stream>>>(wo, woT, 256, 256);
    transposeW_kernel<<<dim3(256 / 32, 256 / 32), 256, 0, stream>>>(wo + 65536, woT + 65536, 256, 256);
    transposeW_kernel<<<dim3(1024 / 32, 256 / 32), 256, 0, stream>>>(mw1, mw1T, 256, 1024);
    transposeW_kernel<<<dim3(1024 / 32, 256 / 32), 256, 0, stream>>>(mw1 + 262144, mw1T + 262144, 256, 1024);
    transposeW_kernel<<<dim3(256 / 32, 1024 / 32), 256, 0, stream>>>(mw2, mw2T, 1024, 256);
    transposeW_kernel<<<dim3(256 / 32, 1024 / 32), 256, 0, stream>>>(mw2 + 262144, mw2T + 262144, 1024, 256);

    pe_kernel<<<512, 256, 0, stream>>>(pe_w1, pe_b1, pe_w2, PE);
    add_pe0_kernel<<<ROWS0, 256, 0, stream>>>(scale0, PE, out);
    pool_kernel<<<ROWS1, 256, 0, stream>>>(out, scale1, PE + 65536, o1sec);

    sattn(o1sec, ROWS1, 16, 1);
    for (int c = 0; c < NC; c++)
        sattn(out + (size_t)c * R * 256, R, CW, 0);

    gather_g_kernel<<<4096, 256, 0, stream>>>(o1sec, G);
    ln16_kernel<<<4096, 256, 0, stream>>>(G, ln1_g + 256, ln1_b + 256, bufH16);
    hgemm(bufH16, wqkvT + 196608, bqkv + 768, nullptr, Q16, 4096, 256, 256, 0);
    for (int c = 0; c < NC; c++) {
        float* xch = out + (size_t)c * R * 256;
        ln16_kernel<<<R, 256, 0, stream>>>(xch, ln1_g + 256, ln1_b + 256, bufH16);
        hgemm(bufH16, wqkvT + 196608 + 65536, bqkv + 768 + 256, nullptr, qkv16, R, 512, 256, 0);
        cross_attn_kernel<<<CW * 16, 128, 0, stream>>>(Q16, qkv16, OX16, c * CW);
    }
    hgemm(OX16, woT + 65536, bo + 256, G, G, 4096, 256, 256, 0);
    ln16_kernel<<<4096, 256, 0, stream>>>(G, ln2_g + 256, ln2_b + 256, bufH16);
    hgemm(bufH16, mw1T + 262144, mb1 + 1024, nullptr, hid16, 4096, 1024, 256, 1);
    hgemm(hid16, mw2T + 262144, mb2 + 256, G, G, 4096, 256, 1024, 0);
    scatter_g_kernel<<<4096, 256, 0, stream>>>(G, o1sec);
}

// Round 4
// 914.585 us; speedup vs baseline: 4.6233x; 1.0255x over previous
//
#include <hip/hip_runtime.h>
#include <hip/hip_bf16.h>
#include <hip/hip_fp16.h>

// B=4, H=8, W=8, M=16, C=256, NH=8, HD=32, GW=2
#define ROWS0 65536
#define ROWS1 4096

typedef _Float16 half8 __attribute__((ext_vector_type(8)));
typedef _Float16 half4_t __attribute__((ext_vector_type(4)));
typedef float floatx4 __attribute__((ext_vector_type(4)));

#define LDSP(p) ((__attribute__((address_space(3))) void*)(p))
#define GLBP(p) ((const __attribute__((address_space(1))) void*)(p))

__device__ __forceinline__ float gelu_f(float x) {
    return 0.5f * x * (1.0f + erff(x * 0.70710678118654752f));
}

// ---------- posemb table ----------
__global__ __launch_bounds__(256) void pe_kernel(
    const float* __restrict__ w1, const float* __restrict__ b1,
    const float* __restrict__ w2, float* __restrict__ pe)
{
    __shared__ float hid[512];
    int blk = blockIdx.x;
    int s = blk >> 8, n = blk & 255;
    int i = n >> 4, j = n & 15;
    float c0 = (i - 8) * 0.125f;
    float c1 = (j - 8) * 0.125f;
    int t = threadIdx.x;
    for (int hh = t; hh < 512; hh += 256) {
        float hv = c0 * w1[s * 1024 + hh] + c1 * w1[s * 1024 + 512 + hh] + b1[s * 512 + hh];
        hid[hh] = fmaxf(hv, 0.f);
    }
    __syncthreads();
    float o = 0.f;
    const float* w2p = w2 + (size_t)s * 512 * 256 + t;
    #pragma unroll 8
    for (int hh = 0; hh < 512; hh++) o += hid[hh] * w2p[hh * 256];
    pe[(size_t)s * 65536 + n * 256 + t] = o;
}

__global__ __launch_bounds__(256) void add_pe0_kernel(
    const float* __restrict__ s0, const float* __restrict__ pe, float* __restrict__ out)
{
    int row = blockIdx.x, c = threadIdx.x;
    out[(size_t)row * 256 + c] = s0[(size_t)row * 256 + c] + pe[(row & 255) * 256 + c];
}

__global__ __launch_bounds__(256) void pool_kernel(
    const float* __restrict__ x0, const float* __restrict__ s1,
    const float* __restrict__ pe1, float* __restrict__ x1out)
{
    int w1 = blockIdx.x >> 8, n1 = blockIdx.x & 255, c = threadIdx.x;
    int b = w1 >> 2, wy = (w1 >> 1) & 1, wx = w1 & 1;
    int ty = n1 >> 4, tx = n1 & 15;
    int gy = wy * 16 + ty, gx = wx * 16 + tx;
    int h = gy >> 2, r1 = gy & 3, w = gx >> 2, r2 = gx & 3;
    int fw = (b * 8 + h) * 8 + w;
    const float* base = x0 + ((size_t)fw * 256 + r1 * 64 + r2 * 4) * 256 + c;
    float mv = -1e30f;
    #pragma unroll
    for (int p1 = 0; p1 < 4; p1++)
        #pragma unroll
        for (int p2 = 0; p2 < 4; p2++)
            mv = fmaxf(mv, base[(p1 * 16 + p2) * 256]);
    size_t oidx = ((size_t)w1 * 256 + n1) * 256 + c;
    x1out[oidx] = s1[oidx] + pe1[n1 * 256 + c] + mv;
}

// ---------- LayerNorm -> fp16 ----------
__global__ __launch_bounds__(256) void ln16_kernel(
    const float* __restrict__ X, const float* __restrict__ g,
    const float* __restrict__ b, _Float16* __restrict__ Y)
{
    __shared__ float smr[4];
    int row = blockIdx.x, t = threadIdx.x;
    float x = X[(size_t)row * 256 + t];
    float v = x;
    for (int o = 32; o; o >>= 1) v += __shfl_down(v, o);
    if ((t & 63) == 0) smr[t >> 6] = v;
    __syncthreads();
    float mean = (smr[0] + smr[1] + smr[2] + smr[3]) * (1.0f / 256.0f);
    __syncthreads();
    float d = x - mean;
    float vv = d * d;
    for (int o = 32; o; o >>= 1) vv += __shfl_down(vv, o);
    if ((t & 63) == 0) smr[t >> 6] = vv;
    __syncthreads();
    float var = (smr[0] + smr[1] + smr[2] + smr[3]) * (1.0f / 256.0f);
    float inv = 1.0f / sqrtf(var + 1e-5f);
    Y[(size_t)row * 256 + t] = (_Float16)(d * inv * g[t] + b[t]);
}

// ---------- weight transpose fp32[K,N] -> fp16[N,K] ----------
__global__ __launch_bounds__(256) void transposeW_kernel(
    const float* __restrict__ src, _Float16* __restrict__ dst, int K, int N)
{
    __shared__ float t[32][33];
    int k0 = blockIdx.y * 32, n0 = blockIdx.x * 32;
    int tx = threadIdx.x & 31, ty = threadIdx.x >> 5;
    for (int r = ty; r < 32; r += 8) t[r][tx] = src[(size_t)(k0 + r) * N + n0 + tx];
    __syncthreads();
    for (int r = ty; r < 32; r += 8) dst[(size_t)(n0 + r) * K + k0 + tx] = (_Float16)t[tx][r];
}

// ---------- fp16 MFMA GEMM (128x128 tile, BK=64), XCD-swizzled 1-D grid ----------
// Coalesced LDS-bounce epilogue (16B stores); RES path reads/writes float4.
template<int ACT, int RES, int OUT16>
__global__ __launch_bounds__(256) void hgemm_kernel(
    const _Float16* __restrict__ A, const _Float16* __restrict__ Bw,
    const float* __restrict__ bias, const float* __restrict__ Res,
    void* __restrict__ Yv, int M, int N, int K)
{
    __shared__ alignas(16) _Float16 smem[2 * 128 * 64];
    _Float16* As = smem;
    _Float16* Bs = smem + 8192;
    int tid = threadIdx.x;

    // bijective XCD-chunked swizzle (nwg % 8 == 0 for all our shapes)
    int gx = N >> 7;
    int nwg = gx * (M >> 7);
    int q8 = nwg >> 3;
    int wg = (blockIdx.x & 7) * q8 + (blockIdx.x >> 3);
    int m0 = (wg / gx) << 7, n0 = (wg % gx) << 7;

    int wave = tid >> 6, lane = tid & 63;
    int wr = wave >> 1, wc = wave & 1;
    floatx4 acc[4][4] = {};

    for (int k0 = 0; k0 < K; k0 += 64) {
        #pragma unroll
        for (int p = 0; p < 4; p++) {
            int s = tid + (p << 8);
            int row = s >> 3, phys = s & 7;
            int logc = phys ^ (row & 7);
            const _Float16* ga = A + (size_t)(m0 + row) * K + k0 + logc * 8;
            __builtin_amdgcn_global_load_lds(GLBP(ga), LDSP(&As[s * 8]), 16, 0, 0);
            const _Float16* gb = Bw + (size_t)(n0 + row) * K + k0 + logc * 8;
            __builtin_amdgcn_global_load_lds(GLBP(gb), LDSP(&Bs[s * 8]), 16, 0, 0);
        }
        __syncthreads();
        int r = lane & 15, c = lane >> 4;
        #pragma unroll
        for (int ks = 0; ks < 2; ks++) {
            half8 af[4], bf[4];
            #pragma unroll
            for (int i = 0; i < 4; i++) {
                int ra = wr * 64 + i * 16 + r;
                af[i] = *(const half8*)&As[ra * 64 + (((ks << 2) | c) ^ (ra & 7)) * 8];
                int rb = wc * 64 + i * 16 + r;
                bf[i] = *(const half8*)&Bs[rb * 64 + (((ks << 2) | c) ^ (rb & 7)) * 8];
            }
            #pragma unroll
            for (int i = 0; i < 4; i++)
                #pragma unroll
                for (int j = 0; j < 4; j++)
                    acc[i][j] = __builtin_amdgcn_mfma_f32_16x16x32_f16(af[i], bf[j], acc[i][j], 0, 0, 0);
        }
        __syncthreads();
    }

    int r = lane & 15, qrow = lane >> 4;
    if (OUT16) {
        _Float16* sth = smem + wave * 1024;   // per-wave 16x64 fp16 staging
        #pragma unroll
        for (int i = 0; i < 4; i++) {
            #pragma unroll
            for (int j = 0; j < 4; j++) {
                float bj = bias[n0 + wc * 64 + j * 16 + r];
                #pragma unroll
                for (int reg = 0; reg < 4; reg++) {
                    float v = acc[i][j][reg] + bj;
                    if (ACT) v = gelu_f(v);
                    sth[(qrow * 4 + reg) * 64 + j * 16 + r] = (_Float16)v;
                }
            }
            #pragma unroll
            for (int p = 0; p < 2; p++) {
                int row = p * 8 + (lane >> 3);
                half8 hv = *(const half8*)&sth[row * 64 + (lane & 7) * 8];
                *(half8*)((_Float16*)Yv + (size_t)(m0 + wr * 64 + i * 16 + row) * N
                          + n0 + wc * 64 + (lane & 7) * 8) = hv;
            }
        }
    } else {
        float* stf = (float*)smem + wave * 1024;  // per-wave 16x64 fp32 staging
        #pragma unroll
        for (int i = 0; i < 4; i++) {
            #pragma unroll
            for (int j = 0; j < 4; j++) {
                float bj = bias[n0 + wc * 64 + j * 16 + r];
                #pragma unroll
                for (int reg = 0; reg < 4; reg++) {
                    float v = acc[i][j][reg] + bj;
                    if (ACT) v = gelu_f(v);
                    stf[(qrow * 4 + reg) * 64 + j * 16 + r] = v;
                }
            }
            #pragma unroll
            for (int p = 0; p < 4; p++) {
                int row = p * 4 + (lane >> 4);
                float4 fv = *(const float4*)&stf[row * 64 + (lane & 15) * 4];
                size_t ga = (size_t)(m0 + wr * 64 + i * 16 + row) * N
                            + n0 + wc * 64 + (lane & 15) * 4;
                if (RES) {
                    float4 rv = *(const float4*)(Res + ga);
                    fv.x += rv.x; fv.y += rv.y; fv.z += rv.z; fv.w += rv.w;
                }
                *(float4*)((float*)Yv + ga) = fv;
            }
        }
    }
}

// ---------- MFMA self-attention: one (window, head) per block, 4 waves ----------
__global__ __launch_bounds__(256) void attn_mfma_kernel(
    const _Float16* __restrict__ qkv, _Float16* __restrict__ out)
{
    __shared__ alignas(16) _Float16 Klds[8192];
    __shared__ alignas(16) _Float16 Qlds[8192];
    __shared__ alignas(16) _Float16 VT[8192];
    __shared__ alignas(16) _Float16 Pl[4][4096];

    int tid = threadIdx.x;
    int win = blockIdx.x, head = blockIdx.y;
    int w = tid >> 6, lane = tid & 63;
    int r = lane & 15, h = lane >> 4;

    {
        const _Float16* base = qkv + ((size_t)(win * 256 + tid)) * 768 + head * 32;
        half8 qv[4], kv[4], vv[4];
        #pragma unroll
        for (int c = 0; c < 4; c++) {
            qv[c] = *(const half8*)(base + c * 8);
            kv[c] = *(const half8*)(base + 256 + c * 8);
            vv[c] = *(const half8*)(base + 512 + c * 8);
        }
        int rowbase = (tid >> 1) * 64;
        #pragma unroll
        for (int c = 0; c < 4; c++) {
            int phys = (((tid & 1) << 2) + c) ^ ((tid >> 1) & 7);
            *(half8*)&Qlds[rowbase + phys * 8] = qv[c];
            *(half8*)&Klds[rowbase + phys * 8] = kv[c];
        }
        #pragma unroll
        for (int d = 0; d < 32; d++)
            VT[d * 256 + (((tid >> 3) ^ (d & 7)) << 3) + (tid & 7)] = vv[d >> 3][d & 7];
    }
    __syncthreads();

    half8 vf[2][8];
    #pragma unroll
    for (int dc = 0; dc < 2; dc++)
        #pragma unroll
        for (int kc2 = 0; kc2 < 8; kc2++)
            vf[dc][kc2] = *(const half8*)&VT[(dc * 16 + r) * 256 + ((((kc2 << 2) + h) ^ (r & 7)) << 3)];

    const floatx4 zf = {0.f, 0.f, 0.f, 0.f};
    int physa = (((r & 1) << 2) + h) ^ ((r >> 1) & 7);

    for (int g = 0; g < 4; g++) {
        int qg = (w << 2) + g;
        half8 qb = *(const half8*)&Qlds[((qg << 3) + (r >> 1)) * 64 + physa * 8];
        floatx4 s[16];
        #pragma unroll
        for (int kc = 0; kc < 16; kc++) {
            half8 ka = *(const half8*)&Klds[((kc << 3) + (r >> 1)) * 64 + physa * 8];
            s[kc] = __builtin_amdgcn_mfma_f32_16x16x32_f16(ka, qb, zf, 0, 0, 0);
        }
        float m = -1e30f;
        #pragma unroll
        for (int kc = 0; kc < 16; kc++)
            #pragma unroll
            for (int e = 0; e < 4; e++) m = fmaxf(m, s[kc][e]);
        m = fmaxf(m, __shfl_xor(m, 16));
        m = fmaxf(m, __shfl_xor(m, 32));
        float l = 0.f;
        #pragma unroll
        for (int kc = 0; kc < 16; kc++)
            #pragma unroll
            for (int e = 0; e < 4; e++) {
                float p = __expf((s[kc][e] - m) * 0.17677669529663687f);
                s[kc][e] = p;
                l += p;
            }
        l += __shfl_xor(l, 16);
        l += __shfl_xor(l, 32);
        float inv = 1.0f / l;
        #pragma unroll
        for (int kc = 0; kc < 16; kc++) {
            half4_t pk;
            pk[0] = (_Float16)s[kc][0]; pk[1] = (_Float16)s[kc][1];
            pk[2] = (_Float16)s[kc][2]; pk[3] = (_Float16)s[kc][3];
            *(half4_t*)&Pl[w][r * 256 + ((((kc << 1) + (h >> 1)) ^ (r & 7)) << 3) + ((h & 1) << 2)] = pk;
        }
        floatx4 o0 = zf, o1 = zf;
        #pragma unroll
        for (int kc2 = 0; kc2 < 8; kc2++) {
            half8 pb = *(const half8*)&Pl[w][r * 256 + ((((kc2 << 2) + h) ^ (r & 7)) << 3)];
            o0 = __builtin_amdgcn_mfma_f32_16x16x32_f16(vf[0][kc2], pb, o0, 0, 0, 0);
            o1 = __builtin_amdgcn_mfma_f32_16x16x32_f16(vf[1][kc2], pb, o1, 0, 0, 0);
        }
        #pragma unroll
        for (int dc = 0; dc < 2; dc++) {
            floatx4 o = dc ? o1 : o0;
            half4_t oh;
            #pragma unroll
            for (int e = 0; e < 4; e++) oh[e] = (_Float16)(o[e] * inv);
            *(half4_t*)&Pl[w][(r >> 1) * 64 + (((((r & 1) << 2) + (dc << 1) + (h >> 1)) ^ ((r >> 1) & 7)) << 3) + ((h & 1) << 2)] = oh;
        }
        int q2 = lane >> 2, c2 = lane & 3;
        half8 ov = *(const half8*)&Pl[w][(q2 >> 1) * 64 + (((((q2 & 1) << 2) + c2) ^ ((q2 >> 1) & 7)) << 3)];
        *(half8*)(out + ((size_t)(win * 256 + qg * 16 + q2)) * 256 + head * 32 + c2 * 8) = ov;
    }
}

// ---------- one2one cross-attention ----------
__global__ __launch_bounds__(128) void cross_attn_kernel(
    const _Float16* __restrict__ Qb, const _Float16* __restrict__ KV,
    _Float16* __restrict__ Ob, int fw0)
{
    __shared__ float att_s[8][16];
    int t = threadIdx.x;
    int lw = blockIdx.x >> 4;
    int sub = blockIdx.x & 15;
    int r1 = sub >> 2, r2 = sub & 3;
    int gi = (fw0 + lw) * 16 + sub;
    int h = t >> 4, m = t & 15;
    int p1 = m >> 2, p2 = m & 3;
    int lr = lw * 256 + r1 * 64 + p1 * 16 + r2 * 4 + p2;
    const half8* qp = (const half8*)(Qb + (size_t)gi * 256 + h * 32);
    const half8* kp = (const half8*)(KV + (size_t)lr * 512 + h * 32);
    float sc = 0.f;
    #pragma unroll
    for (int d8 = 0; d8 < 4; d8++) {
        half8 qv = qp[d8], kv = kp[d8];
        #pragma unroll
        for (int j = 0; j < 8; j++) sc += (float)qv[j] * (float)kv[j];
    }
    sc *= 0.17677669529663687f;
    float mx = sc;
    for (int o = 8; o; o >>= 1) mx = fmaxf(mx, __shfl_xor(mx, o));
    float e = __expf(sc - mx);
    float ssum = e;
    for (int o = 8; o; o >>= 1) ssum += __shfl_xor(ssum, o);
    att_s[h][m] = e / ssum;
    __syncthreads();
    int dg = t & 15;
    int d0 = dg * 2;
    float o0 = 0.f, o1 = 0.f;
    #pragma unroll
    for (int mm = 0; mm < 16; mm++) {
        int pp1 = mm >> 2, pp2 = mm & 3;
        int lrr = lw * 256 + r1 * 64 + pp1 * 16 + r2 * 4 + pp2;
        const _Float16* vp = KV + (size_t)lrr * 512 + 256 + h * 32;
        float a = att_s[h][mm];
        o0 += a * (float)vp[d0];
        o1 += a * (float)vp[d0 + 1];
    }
    Ob[(size_t)gi * 256 + h * 32 + d0]     = (_Float16)o0;
    Ob[(size_t)gi * 256 + h * 32 + d0 + 1] = (_Float16)o1;
}

// ---------- gather/scatter global tokens ----------
__global__ __launch_bounds__(256) void gather_g_kernel(
    const float* __restrict__ o1, float* __restrict__ G)
{
    int gi = blockIdx.x, c = threadIdx.x;
    int b = gi >> 10, rem = gi & 1023;
    int h = rem >> 7, w = (rem >> 4) & 7, r1 = (rem >> 2) & 3, r2 = rem & 3;
    int gy = h * 4 + r1, gx = w * 4 + r2;
    int w1 = (b * 2 + (gy >> 4)) * 2 + (gx >> 4);
    int n1 = (gy & 15) * 16 + (gx & 15);
    G[(size_t)gi * 256 + c] = o1[((size_t)w1 * 256 + n1) * 256 + c];
}

__global__ __launch_bounds__(256) void scatter_g_kernel(
    const float* __restrict__ G, float* __restrict__ o1)
{
    int gi = blockIdx.x, c = threadIdx.x;
    int b = gi >> 10, rem = gi & 1023;
    int h = rem >> 7, w = (rem >> 4) & 7, r1 = (rem >> 2) & 3, r2 = rem & 3;
    int gy = h * 4 + r1, gx = w * 4 + r2;
    int w1 = (b * 2 + (gy >> 4)) * 2 + (gx >> 4);
    int n1 = (gy & 15) * 16 + (gx & 15);
    o1[((size_t)w1 * 256 + n1) * 256 + c] = G[(size_t)gi * 256 + c];
}

// ---------- host ----------
extern "C" void kernel_launch(void* const* d_in, const int* in_sizes, int n_in,
                              void* d_out, int out_size, void* d_ws, size_t ws_size,
                              hipStream_t stream)
{
    const float* scale0 = (const float*)d_in[0];
    const float* scale1 = (const float*)d_in[1];
    const float* pe_w1  = (const float*)d_in[2];
    const float* pe_b1  = (const float*)d_in[3];
    const float* pe_w2  = (const float*)d_in[4];
    const float* ln1_g  = (const float*)d_in[5];
    const float* ln1_b  = (const float*)d_in[6];
    const float* wqkv   = (const float*)d_in[7];
    const float* bqkv   = (const float*)d_in[8];
    const float* wo     = (const float*)d_in[9];
    const float* bo     = (const float*)d_in[10];
    const float* ln2_g  = (const float*)d_in[11];
    const float* ln2_b  = (const float*)d_in[12];
    const float* mw1    = (const float*)d_in[13];
    const float* mb1    = (const float*)d_in[14];
    const float* mw2    = (const float*)d_in[15];
    const float* mb2    = (const float*)d_in[16];
    float* out = (float*)d_out;
    char* arena = (char*)d_ws;

    float*    PE     = (float*)arena;              arena += 131072 * 4;
    float*    G      = (float*)arena;              arena += (size_t)4096 * 256 * 4;
    _Float16* Q16    = (_Float16*)arena;           arena += (size_t)4096 * 256 * 2;
    _Float16* OX16   = (_Float16*)arena;           arena += (size_t)4096 * 256 * 2;
    _Float16* wqkvT  = (_Float16*)arena;           arena += (size_t)2 * 768 * 256 * 2;
    _Float16* woT    = (_Float16*)arena;           arena += (size_t)2 * 256 * 256 * 2;
    _Float16* mw1T   = (_Float16*)arena;           arena += (size_t)2 * 1024 * 256 * 2;
    _Float16* mw2T   = (_Float16*)arena;           arena += (size_t)2 * 256 * 1024 * 2;
    size_t fixed_bytes = (size_t)(arena - (char*)d_ws);

    int R = 8192;
    if (fixed_bytes + (size_t)65536 * 4608 <= ws_size) R = 65536;
    else if (fixed_bytes + (size_t)32768 * 4608 <= ws_size) R = 32768;
    else if (fixed_bytes + (size_t)16384 * 4608 <= ws_size) R = 16384;
    int NC = 65536 / R;
    int CW = R / 256;

    _Float16* bufH16 = (_Float16*)arena;           arena += (size_t)R * 256 * 2;
    _Float16* qkv16  = (_Float16*)arena;           arena += (size_t)R * 768 * 2;
    _Float16* hid16  = (_Float16*)arena;           arena += (size_t)R * 1024 * 2;
    _Float16* o16    = (_Float16*)arena;

    auto hgemm = [&](const _Float16* A, const _Float16* Bw, const float* bias,
                     const float* Res, void* Y, int M, int N, int K, int act) {
        int nwg = (N >> 7) * (M >> 7);
        if (act)           hgemm_kernel<1, 0, 1><<<nwg, 256, 0, stream>>>(A, Bw, bias, nullptr, Y, M, N, K);
        else if (Res)      hgemm_kernel<0, 1, 0><<<nwg, 256, 0, stream>>>(A, Bw, bias, Res, Y, M, N, K);
        else               hgemm_kernel<0, 0, 1><<<nwg, 256, 0, stream>>>(A, Bw, bias, nullptr, Y, M, N, K);
    };

    auto sattn = [&](float* x, int Mrows, int nw, int s) {
        ln16_kernel<<<Mrows, 256, 0, stream>>>(x, ln1_g + s * 256, ln1_b + s * 256, bufH16);
        hgemm(bufH16, wqkvT + (size_t)s * 196608, bqkv + s * 768, nullptr, qkv16, Mrows, 768, 256, 0);
        attn_mfma_kernel<<<dim3(nw, 8), 256, 0, stream>>>(qkv16, o16);
        hgemm(o16, woT + (size_t)s * 65536, bo + s * 256, x, x, Mrows, 256, 256, 0);
        ln16_kernel<<<Mrows, 256, 0, stream>>>(x, ln2_g + s * 256, ln2_b + s * 256, bufH16);
        hgemm(bufH16, mw1T + (size_t)s * 262144, mb1 + s * 1024, nullptr, hid16, Mrows, 1024, 256, 1);
        hgemm(hid16, mw2T + (size_t)s * 262144, mb2 + s * 256, x, x, Mrows, 256, 1024, 0);
    };

    float* o1sec = out + (size_t)ROWS0 * 256;

    transposeW_kernel<<<dim3(768 / 32, 256 / 32), 256, 0, stream>>>(wqkv, wqkvT, 256, 768);
    transposeW_kernel<<<dim3(768 / 32, 256 / 32), 256, 0, stream>>>(wqkv + 196608, wqkvT + 196608, 256, 768);
    transposeW_kernel<<<dim3(256 / 32, 256 / 32), 256, 0, stream>>>(wo, woT, 256, 256);
    transposeW_kernel<<<dim3(256 / 32, 256 / 32), 256, 0, stream>>>(wo + 65536, woT + 65536, 256, 256);
    transposeW_kernel<<<dim3(1024 / 32, 256 / 32), 256, 0, stream>>>(mw1, mw1T, 256, 1024);
    transposeW_kernel<<<dim3(1024 / 32, 256 / 32), 256, 0, stream>>>(mw1 + 262144, mw1T + 262144, 256, 1024);
    transposeW_kernel<<<dim3(256 / 32, 1024 / 32), 256, 0, stream>>>(mw2, mw2T, 1024, 256);
    transposeW_kernel<<<dim3(256 / 32, 1024 / 32), 256, 0, stream>>>(mw2 + 262144, mw2T + 262144, 1024, 256);

    pe_kernel<<<512, 256, 0, stream>>>(pe_w1, pe_b1, pe_w2, PE);
    add_pe0_kernel<<<ROWS0, 256, 0, stream>>>(scale0, PE, out);
    pool_kernel<<<ROWS1, 256, 0, stream>>>(out, scale1, PE + 65536, o1sec);

    sattn(o1sec, ROWS1, 16, 1);
    for (int c = 0; c < NC; c++)
        sattn(out + (size_t)c * R * 256, R, CW, 0);

    gather_g_kernel<<<4096, 256, 0, stream>>>(o1sec, G);
    ln16_kernel<<<4096, 256, 0, stream>>>(G, ln1_g + 256, ln1_b + 256, bufH16);
    hgemm(bufH16, wqkvT + 196608, bqkv + 768, nullptr, Q16, 4096, 256, 256, 0);
    for (int c = 0; c < NC; c++) {
        float* xch = out + (size_t)c * R * 256;
        ln16_kernel<<<R, 256, 0, stream>>>(xch, ln1_g + 256, ln1_b + 256, bufH16);
        hgemm(bufH16, wqkvT + 196608 + 65536, bqkv + 768 + 256, nullptr, qkv16, R, 512, 256, 0);
        cross_attn_kernel<<<CW * 16, 128, 0, stream>>>(Q16, qkv16, OX16, c * CW);
    }
    hgemm(OX16, woT + 65536, bo + 256, G, G, 4096, 256, 256, 0);
    ln16_kernel<<<4096, 256, 0, stream>>>(G, ln2_g + 256, ln2_b + 256, bufH16);
    hgemm(bufH16, mw1T + 262144, mb1 + 1024, nullptr, hid16, 4096, 1024, 256, 1);
    hgemm(hid16, mw2T + 262144, mb2 + 256, G, G, 4096, 256, 1024, 0);
    scatter_g_kernel<<<4096, 256, 0, stream>>>(G, o1sec);
}

// Round 5
// 865.074 us; speedup vs baseline: 4.8879x; 1.0572x over previous
//
#include <hip/hip_runtime.h>
#include <hip/hip_bf16.h>
#include <hip/hip_fp16.h>

// B=4, H=8, W=8, M=16, C=256, NH=8, HD=32, GW=2
#define ROWS0 65536
#define ROWS1 4096

typedef _Float16 half8 __attribute__((ext_vector_type(8)));
typedef _Float16 half4_t __attribute__((ext_vector_type(4)));
typedef float floatx4 __attribute__((ext_vector_type(4)));

#define LDSP(p) ((__attribute__((address_space(3))) void*)(p))
#define GLBP(p) ((const __attribute__((address_space(1))) void*)(p))

// tanh-form GELU: x * sigmoid(1.5957691x + 0.0713548x^3), one v_exp_f32.
__device__ __forceinline__ float gelu_f(float x) {
    float t = x * (1.595769122f + 0.071354816f * x * x);
    return x / (1.0f + __expf(-t));
}

// ---------- posemb table ----------
__global__ __launch_bounds__(256) void pe_kernel(
    const float* __restrict__ w1, const float* __restrict__ b1,
    const float* __restrict__ w2, float* __restrict__ pe)
{
    __shared__ float hid[512];
    int blk = blockIdx.x;
    int s = blk >> 8, n = blk & 255;
    int i = n >> 4, j = n & 15;
    float c0 = (i - 8) * 0.125f;
    float c1 = (j - 8) * 0.125f;
    int t = threadIdx.x;
    for (int hh = t; hh < 512; hh += 256) {
        float hv = c0 * w1[s * 1024 + hh] + c1 * w1[s * 1024 + 512 + hh] + b1[s * 512 + hh];
        hid[hh] = fmaxf(hv, 0.f);
    }
    __syncthreads();
    float o = 0.f;
    const float* w2p = w2 + (size_t)s * 512 * 256 + t;
    #pragma unroll 8
    for (int hh = 0; hh < 512; hh++) o += hid[hh] * w2p[hh * 256];
    pe[(size_t)s * 65536 + n * 256 + t] = o;
}

__global__ __launch_bounds__(256) void add_pe0_kernel(
    const float* __restrict__ s0, const float* __restrict__ pe, float* __restrict__ out)
{
    int row = blockIdx.x, c = threadIdx.x;
    out[(size_t)row * 256 + c] = s0[(size_t)row * 256 + c] + pe[(row & 255) * 256 + c];
}

__global__ __launch_bounds__(256) void pool_kernel(
    const float* __restrict__ x0, const float* __restrict__ s1,
    const float* __restrict__ pe1, float* __restrict__ x1out)
{
    int w1 = blockIdx.x >> 8, n1 = blockIdx.x & 255, c = threadIdx.x;
    int b = w1 >> 2, wy = (w1 >> 1) & 1, wx = w1 & 1;
    int ty = n1 >> 4, tx = n1 & 15;
    int gy = wy * 16 + ty, gx = wx * 16 + tx;
    int h = gy >> 2, r1 = gy & 3, w = gx >> 2, r2 = gx & 3;
    int fw = (b * 8 + h) * 8 + w;
    const float* base = x0 + ((size_t)fw * 256 + r1 * 64 + r2 * 4) * 256 + c;
    float mv = -1e30f;
    #pragma unroll
    for (int p1 = 0; p1 < 4; p1++)
        #pragma unroll
        for (int p2 = 0; p2 < 4; p2++)
            mv = fmaxf(mv, base[(p1 * 16 + p2) * 256]);
    size_t oidx = ((size_t)w1 * 256 + n1) * 256 + c;
    x1out[oidx] = s1[oidx] + pe1[n1 * 256 + c] + mv;
}

// ---------- LayerNorm -> fp16 ----------
__global__ __launch_bounds__(256) void ln16_kernel(
    const float* __restrict__ X, const float* __restrict__ g,
    const float* __restrict__ b, _Float16* __restrict__ Y)
{
    __shared__ float smr[4];
    int row = blockIdx.x, t = threadIdx.x;
    float x = X[(size_t)row * 256 + t];
    float v = x;
    for (int o = 32; o; o >>= 1) v += __shfl_down(v, o);
    if ((t & 63) == 0) smr[t >> 6] = v;
    __syncthreads();
    float mean = (smr[0] + smr[1] + smr[2] + smr[3]) * (1.0f / 256.0f);
    __syncthreads();
    float d = x - mean;
    float vv = d * d;
    for (int o = 32; o; o >>= 1) vv += __shfl_down(vv, o);
    if ((t & 63) == 0) smr[t >> 6] = vv;
    __syncthreads();
    float var = (smr[0] + smr[1] + smr[2] + smr[3]) * (1.0f / 256.0f);
    float inv = 1.0f / sqrtf(var + 1e-5f);
    Y[(size_t)row * 256 + t] = (_Float16)(d * inv * g[t] + b[t]);
}

// ---------- weight transpose fp32[K,N] -> fp16[N,K] ----------
__global__ __launch_bounds__(256) void transposeW_kernel(
    const float* __restrict__ src, _Float16* __restrict__ dst, int K, int N)
{
    __shared__ float t[32][33];
    int k0 = blockIdx.y * 32, n0 = blockIdx.x * 32;
    int tx = threadIdx.x & 31, ty = threadIdx.x >> 5;
    for (int r = ty; r < 32; r += 8) t[r][tx] = src[(size_t)(k0 + r) * N + n0 + tx];
    __syncthreads();
    for (int r = ty; r < 32; r += 8) dst[(size_t)(n0 + r) * K + k0 + tx] = (_Float16)t[tx][r];
}

// ---------- fp16 MFMA GEMM: 128x128 tile, BK=32, 2-phase double-buffered ----------
// XCD-swizzled 1-D grid; padded LDS-bounce epilogue (conflict-free, 16B stores).
template<int ACT, int RES, int OUT16>
__global__ __launch_bounds__(256) void hgemm_kernel(
    const _Float16* __restrict__ A, const _Float16* __restrict__ Bw,
    const float* __restrict__ bias, const float* __restrict__ Res,
    void* __restrict__ Yv, int M, int N, int K)
{
    __shared__ alignas(16) _Float16 smem[4 * 4096];  // As[2] | Bs[2], 8KB each
    int tid = threadIdx.x;

    // bijective XCD-chunked swizzle (nwg % 8 == 0 for all our shapes)
    int gx = N >> 7;
    int nwg = gx * (M >> 7);
    int q8 = nwg >> 3;
    int wg = (blockIdx.x & 7) * q8 + (blockIdx.x >> 3);
    int m0 = (wg / gx) << 7, n0 = (wg % gx) << 7;

    int wave = tid >> 6, lane = tid & 63;
    int wr = wave >> 1, wc = wave & 1;
    int r = lane & 15, c = lane >> 4;
    floatx4 acc[4][4] = {};

    const int NT = K >> 5;

    auto stage = [&](int buf, int t) {
        int k0 = t << 5;
        #pragma unroll
        for (int p = 0; p < 2; p++) {
            int s = tid + (p << 8);                  // 0..511
            int row = s >> 2, phys = s & 3;
            int logc = phys ^ (row & 3);
            const _Float16* ga = A + (size_t)(m0 + row) * K + k0 + logc * 8;
            __builtin_amdgcn_global_load_lds(GLBP(ga), LDSP(&smem[buf * 4096 + s * 8]), 16, 0, 0);
            const _Float16* gb = Bw + (size_t)(n0 + row) * K + k0 + logc * 8;
            __builtin_amdgcn_global_load_lds(GLBP(gb), LDSP(&smem[8192 + buf * 4096 + s * 8]), 16, 0, 0);
        }
    };

    stage(0, 0);
    __syncthreads();
    int cur = 0;
    for (int t = 0; t < NT; t++) {
        if (t + 1 < NT) stage(cur ^ 1, t + 1);      // prefetch overlaps compute
        const _Float16* As = &smem[cur * 4096];
        const _Float16* Bs = &smem[8192 + cur * 4096];
        half8 af[4], bf[4];
        #pragma unroll
        for (int i = 0; i < 4; i++) {
            int ra = wr * 64 + i * 16 + r;
            af[i] = *(const half8*)&As[ra * 32 + ((c ^ (ra & 3)) << 3)];
            int rb = wc * 64 + i * 16 + r;
            bf[i] = *(const half8*)&Bs[rb * 32 + ((c ^ (rb & 3)) << 3)];
        }
        #pragma unroll
        for (int i = 0; i < 4; i++)
            #pragma unroll
            for (int j = 0; j < 4; j++)
                acc[i][j] = __builtin_amdgcn_mfma_f32_16x16x32_f16(af[i], bf[j], acc[i][j], 0, 0, 0);
        __syncthreads();                             // drains vmcnt: prefetched tile ready
        cur ^= 1;
    }

    int qrow = lane >> 4;
    if (OUT16) {
        _Float16* sth = smem + wave * 1152;          // 16 x 72 halves (144B rows, 16B aligned)
        #pragma unroll
        for (int i = 0; i < 4; i++) {
            #pragma unroll
            for (int j = 0; j < 4; j++) {
                float bj = bias[n0 + wc * 64 + j * 16 + r];
                #pragma unroll
                for (int reg = 0; reg < 4; reg++) {
                    float v = acc[i][j][reg] + bj;
                    if (ACT) v = gelu_f(v);
                    sth[(qrow * 4 + reg) * 72 + j * 16 + r] = (_Float16)v;
                }
            }
            #pragma unroll
            for (int p = 0; p < 2; p++) {
                int row = p * 8 + (lane >> 3);
                half8 hv = *(const half8*)&sth[row * 72 + (lane & 7) * 8];
                *(half8*)((_Float16*)Yv + (size_t)(m0 + wr * 64 + i * 16 + row) * N
                          + n0 + wc * 64 + (lane & 7) * 8) = hv;
            }
        }
    } else {
        float* stf = (float*)smem + wave * 1088;     // 16 x 68 floats (272B rows, 16B aligned)
        #pragma unroll
        for (int i = 0; i < 4; i++) {
            #pragma unroll
            for (int j = 0; j < 4; j++) {
                float bj = bias[n0 + wc * 64 + j * 16 + r];
                #pragma unroll
                for (int reg = 0; reg < 4; reg++) {
                    float v = acc[i][j][reg] + bj;
                    if (ACT) v = gelu_f(v);
                    stf[(qrow * 4 + reg) * 68 + j * 16 + r] = v;
                }
            }
            #pragma unroll
            for (int p = 0; p < 4; p++) {
                int row = p * 4 + (lane >> 4);
                float4 fv = *(const float4*)&stf[row * 68 + (lane & 15) * 4];
                size_t ga = (size_t)(m0 + wr * 64 + i * 16 + row) * N
                            + n0 + wc * 64 + (lane & 15) * 4;
                if (RES) {
                    float4 rv = *(const float4*)(Res + ga);
                    fv.x += rv.x; fv.y += rv.y; fv.z += rv.z; fv.w += rv.w;
                }
                *(float4*)((float*)Yv + ga) = fv;
            }
        }
    }
}

// ---------- MFMA self-attention: one (window, head) per block, 4 waves ----------
__global__ __launch_bounds__(256) void attn_mfma_kernel(
    const _Float16* __restrict__ qkv, _Float16* __restrict__ out)
{
    __shared__ alignas(16) _Float16 Klds[8192];
    __shared__ alignas(16) _Float16 Qlds[8192];
    __shared__ alignas(16) _Float16 VT[8192];
    __shared__ alignas(16) _Float16 Pl[4][4096];

    int tid = threadIdx.x;
    int win = blockIdx.x, head = blockIdx.y;
    int w = tid >> 6, lane = tid & 63;
    int r = lane & 15, h = lane >> 4;

    {
        const _Float16* base = qkv + ((size_t)(win * 256 + tid)) * 768 + head * 32;
        half8 qv[4], kv[4], vv[4];
        #pragma unroll
        for (int c = 0; c < 4; c++) {
            qv[c] = *(const half8*)(base + c * 8);
            kv[c] = *(const half8*)(base + 256 + c * 8);
            vv[c] = *(const half8*)(base + 512 + c * 8);
        }
        int rowbase = (tid >> 1) * 64;
        #pragma unroll
        for (int c = 0; c < 4; c++) {
            int phys = (((tid & 1) << 2) + c) ^ ((tid >> 1) & 7);
            *(half8*)&Qlds[rowbase + phys * 8] = qv[c];
            *(half8*)&Klds[rowbase + phys * 8] = kv[c];
        }
        #pragma unroll
        for (int d = 0; d < 32; d++)
            VT[d * 256 + (((tid >> 3) ^ (d & 7)) << 3) + (tid & 7)] = vv[d >> 3][d & 7];
    }
    __syncthreads();

    half8 vf[2][8];
    #pragma unroll
    for (int dc = 0; dc < 2; dc++)
        #pragma unroll
        for (int kc2 = 0; kc2 < 8; kc2++)
            vf[dc][kc2] = *(const half8*)&VT[(dc * 16 + r) * 256 + ((((kc2 << 2) + h) ^ (r & 7)) << 3)];

    const floatx4 zf = {0.f, 0.f, 0.f, 0.f};
    int physa = (((r & 1) << 2) + h) ^ ((r >> 1) & 7);

    for (int g = 0; g < 4; g++) {
        int qg = (w << 2) + g;
        half8 qb = *(const half8*)&Qlds[((qg << 3) + (r >> 1)) * 64 + physa * 8];
        floatx4 s[16];
        #pragma unroll
        for (int kc = 0; kc < 16; kc++) {
            half8 ka = *(const half8*)&Klds[((kc << 3) + (r >> 1)) * 64 + physa * 8];
            s[kc] = __builtin_amdgcn_mfma_f32_16x16x32_f16(ka, qb, zf, 0, 0, 0);
        }
        float m = -1e30f;
        #pragma unroll
        for (int kc = 0; kc < 16; kc++)
            #pragma unroll
            for (int e = 0; e < 4; e++) m = fmaxf(m, s[kc][e]);
        m = fmaxf(m, __shfl_xor(m, 16));
        m = fmaxf(m, __shfl_xor(m, 32));
        float l = 0.f;
        #pragma unroll
        for (int kc = 0; kc < 16; kc++)
            #pragma unroll
            for (int e = 0; e < 4; e++) {
                float p = __expf((s[kc][e] - m) * 0.17677669529663687f);
                s[kc][e] = p;
                l += p;
            }
        l += __shfl_xor(l, 16);
        l += __shfl_xor(l, 32);
        float inv = 1.0f / l;
        #pragma unroll
        for (int kc = 0; kc < 16; kc++) {
            half4_t pk;
            pk[0] = (_Float16)s[kc][0]; pk[1] = (_Float16)s[kc][1];
            pk[2] = (_Float16)s[kc][2]; pk[3] = (_Float16)s[kc][3];
            *(half4_t*)&Pl[w][r * 256 + ((((kc << 1) + (h >> 1)) ^ (r & 7)) << 3) + ((h & 1) << 2)] = pk;
        }
        floatx4 o0 = zf, o1 = zf;
        #pragma unroll
        for (int kc2 = 0; kc2 < 8; kc2++) {
            half8 pb = *(const half8*)&Pl[w][r * 256 + ((((kc2 << 2) + h) ^ (r & 7)) << 3)];
            o0 = __builtin_amdgcn_mfma_f32_16x16x32_f16(vf[0][kc2], pb, o0, 0, 0, 0);
            o1 = __builtin_amdgcn_mfma_f32_16x16x32_f16(vf[1][kc2], pb, o1, 0, 0, 0);
        }
        #pragma unroll
        for (int dc = 0; dc < 2; dc++) {
            floatx4 o = dc ? o1 : o0;
            half4_t oh;
            #pragma unroll
            for (int e = 0; e < 4; e++) oh[e] = (_Float16)(o[e] * inv);
            *(half4_t*)&Pl[w][(r >> 1) * 64 + (((((r & 1) << 2) + (dc << 1) + (h >> 1)) ^ ((r >> 1) & 7)) << 3) + ((h & 1) << 2)] = oh;
        }
        int q2 = lane >> 2, c2 = lane & 3;
        half8 ov = *(const half8*)&Pl[w][(q2 >> 1) * 64 + (((((q2 & 1) << 2) + c2) ^ ((q2 >> 1) & 7)) << 3)];
        *(half8*)(out + ((size_t)(win * 256 + qg * 16 + q2)) * 256 + head * 32 + c2 * 8) = ov;
    }
}

// ---------- one2one cross-attention ----------
__global__ __launch_bounds__(128) void cross_attn_kernel(
    const _Float16* __restrict__ Qb, const _Float16* __restrict__ KV,
    _Float16* __restrict__ Ob, int fw0)
{
    __shared__ float att_s[8][16];
    int t = threadIdx.x;
    int lw = blockIdx.x >> 4;
    int sub = blockIdx.x & 15;
    int r1 = sub >> 2, r2 = sub & 3;
    int gi = (fw0 + lw) * 16 + sub;
    int h = t >> 4, m = t & 15;
    int p1 = m >> 2, p2 = m & 3;
    int lr = lw * 256 + r1 * 64 + p1 * 16 + r2 * 4 + p2;
    const half8* qp = (const half8*)(Qb + (size_t)gi * 256 + h * 32);
    const half8* kp = (const half8*)(KV + (size_t)lr * 512 + h * 32);
    float sc = 0.f;
    #pragma unroll
    for (int d8 = 0; d8 < 4; d8++) {
        half8 qv = qp[d8], kv = kp[d8];
        #pragma unroll
        for (int j = 0; j < 8; j++) sc += (float)qv[j] * (float)kv[j];
    }
    sc *= 0.17677669529663687f;
    float mx = sc;
    for (int o = 8; o; o >>= 1) mx = fmaxf(mx, __shfl_xor(mx, o));
    float e = __expf(sc - mx);
    float ssum = e;
    for (int o = 8; o; o >>= 1) ssum += __shfl_xor(ssum, o);
    att_s[h][m] = e / ssum;
    __syncthreads();
    int dg = t & 15;
    int d0 = dg * 2;
    float o0 = 0.f, o1 = 0.f;
    #pragma unroll
    for (int mm = 0; mm < 16; mm++) {
        int pp1 = mm >> 2, pp2 = mm & 3;
        int lrr = lw * 256 + r1 * 64 + pp1 * 16 + r2 * 4 + pp2;
        const _Float16* vp = KV + (size_t)lrr * 512 + 256 + h * 32;
        float a = att_s[h][mm];
        o0 += a * (float)vp[d0];
        o1 += a * (float)vp[d0 + 1];
    }
    Ob[(size_t)gi * 256 + h * 32 + d0]     = (_Float16)o0;
    Ob[(size_t)gi * 256 + h * 32 + d0 + 1] = (_Float16)o1;
}

// ---------- gather/scatter global tokens ----------
__global__ __launch_bounds__(256) void gather_g_kernel(
    const float* __restrict__ o1, float* __restrict__ G)
{
    int gi = blockIdx.x, c = threadIdx.x;
    int b = gi >> 10, rem = gi & 1023;
    int h = rem >> 7, w = (rem >> 4) & 7, r1 = (rem >> 2) & 3, r2 = rem & 3;
    int gy = h * 4 + r1, gx = w * 4 + r2;
    int w1 = (b * 2 + (gy >> 4)) * 2 + (gx >> 4);
    int n1 = (gy & 15) * 16 + (gx & 15);
    G[(size_t)gi * 256 + c] = o1[((size_t)w1 * 256 + n1) * 256 + c];
}

__global__ __launch_bounds__(256) void scatter_g_kernel(
    const float* __restrict__ G, float* __restrict__ o1)
{
    int gi = blockIdx.x, c = threadIdx.x;
    int b = gi >> 10, rem = gi & 1023;
    int h = rem >> 7, w = (rem >> 4) & 7, r1 = (rem >> 2) & 3, r2 = rem & 3;
    int gy = h * 4 + r1, gx = w * 4 + r2;
    int w1 = (b * 2 + (gy >> 4)) * 2 + (gx >> 4);
    int n1 = (gy & 15) * 16 + (gx & 15);
    o1[((size_t)w1 * 256 + n1) * 256 + c] = G[(size_t)gi * 256 + c];
}

// ---------- host ----------
extern "C" void kernel_launch(void* const* d_in, const int* in_sizes, int n_in,
                              void* d_out, int out_size, void* d_ws, size_t ws_size,
                              hipStream_t stream)
{
    const float* scale0 = (const float*)d_in[0];
    const float* scale1 = (const float*)d_in[1];
    const float* pe_w1  = (const float*)d_in[2];
    const float* pe_b1  = (const float*)d_in[3];
    const float* pe_w2  = (const float*)d_in[4];
    const float* ln1_g  = (const float*)d_in[5];
    const float* ln1_b  = (const float*)d_in[6];
    const float* wqkv   = (const float*)d_in[7];
    const float* bqkv   = (const float*)d_in[8];
    const float* wo     = (const float*)d_in[9];
    const float* bo     = (const float*)d_in[10];
    const float* ln2_g  = (const float*)d_in[11];
    const float* ln2_b  = (const float*)d_in[12];
    const float* mw1    = (const float*)d_in[13];
    const float* mb1    = (const float*)d_in[14];
    const float* mw2    = (const float*)d_in[15];
    const float* mb2    = (const float*)d_in[16];
    float* out = (float*)d_out;
    char* arena = (char*)d_ws;

    float*    PE     = (float*)arena;              arena += 131072 * 4;
    float*    G      = (float*)arena;              arena += (size_t)4096 * 256 * 4;
    _Float16* Q16    = (_Float16*)arena;           arena += (size_t)4096 * 256 * 2;
    _Float16* OX16   = (_Float16*)arena;           arena += (size_t)4096 * 256 * 2;
    _Float16* wqkvT  = (_Float16*)arena;           arena += (size_t)2 * 768 * 256 * 2;
    _Float16* woT    = (_Float16*)arena;           arena += (size_t)2 * 256 * 256 * 2;
    _Float16* mw1T   = (_Float16*)arena;           arena += (size_t)2 * 1024 * 256 * 2;
    _Float16* mw2T   = (_Float16*)arena;           arena += (size_t)2 * 256 * 1024 * 2;
    size_t fixed_bytes = (size_t)(arena - (char*)d_ws);

    int R = 8192;
    if (fixed_bytes + (size_t)65536 * 4608 <= ws_size) R = 65536;
    else if (fixed_bytes + (size_t)32768 * 4608 <= ws_size) R = 32768;
    else if (fixed_bytes + (size_t)16384 * 4608 <= ws_size) R = 16384;
    int NC = 65536 / R;
    int CW = R / 256;

    _Float16* bufH16 = (_Float16*)arena;           arena += (size_t)R * 256 * 2;
    _Float16* qkv16  = (_Float16*)arena;           arena += (size_t)R * 768 * 2;
    _Float16* hid16  = (_Float16*)arena;           arena += (size_t)R * 1024 * 2;
    _Float16* o16    = (_Float16*)arena;

    auto hgemm = [&](const _Float16* A, const _Float16* Bw, const float* bias,
                     const float* Res, void* Y, int M, int N, int K, int act) {
        int nwg = (N >> 7) * (M >> 7);
        if (act)           hgemm_kernel<1, 0, 1><<<nwg, 256, 0, stream>>>(A, Bw, bias, nullptr, Y, M, N, K);
        else if (Res)      hgemm_kernel<0, 1, 0><<<nwg, 256, 0, stream>>>(A, Bw, bias, Res, Y, M, N, K);
        else               hgemm_kernel<0, 0, 1><<<nwg, 256, 0, stream>>>(A, Bw, bias, nullptr, Y, M, N, K);
    };

    auto sattn = [&](float* x, int Mrows, int nw, int s) {
        ln16_kernel<<<Mrows, 256, 0, stream>>>(x, ln1_g + s * 256, ln1_b + s * 256, bufH16);
        hgemm(bufH16, wqkvT + (size_t)s * 196608, bqkv + s * 768, nullptr, qkv16, Mrows, 768, 256, 0);
        attn_mfma_kernel<<<dim3(nw, 8), 256, 0, stream>>>(qkv16, o16);
        hgemm(o16, woT + (size_t)s * 65536, bo + s * 256, x, x, Mrows, 256, 256, 0);
        ln16_kernel<<<Mrows, 256, 0, stream>>>(x, ln2_g + s * 256, ln2_b + s * 256, bufH16);
        hgemm(bufH16, mw1T + (size_t)s * 262144, mb1 + s * 1024, nullptr, hid16, Mrows, 1024, 256, 1);
        hgemm(hid16, mw2T + (size_t)s * 262144, mb2 + s * 256, x, x, Mrows, 256, 1024, 0);
    };

    float* o1sec = out + (size_t)ROWS0 * 256;

    transposeW_kernel<<<dim3(768 / 32, 256 / 32), 256, 0, stream>>>(wqkv, wqkvT, 256, 768);
    transposeW_kernel<<<dim3(768 / 32, 256 / 32), 256, 0, stream>>>(wqkv + 196608, wqkvT + 196608, 256, 768);
    transposeW_kernel<<<dim3(256 / 32, 256 / 32), 256, 0, stream>>>(wo, woT, 256, 256);
    transposeW_kernel<<<dim3(256 / 32, 256 / 32), 256, 0, stream>>>(wo + 65536, woT + 65536, 256, 256);
    transposeW_kernel<<<dim3(1024 / 32, 256 / 32), 256, 0, stream>>>(mw1, mw1T, 256, 1024);
    transposeW_kernel<<<dim3(1024 / 32, 256 / 32), 256, 0, stream>>>(mw1 + 262144, mw1T + 262144, 256, 1024);
    transposeW_kernel<<<dim3(256 / 32, 1024 / 32), 256, 0, stream>>>(mw2, mw2T, 1024, 256);
    transposeW_kernel<<<dim3(256 / 32, 1024 / 32), 256, 0, stream>>>(mw2 + 262144, mw2T + 262144, 1024, 256);

    pe_kernel<<<512, 256, 0, stream>>>(pe_w1, pe_b1, pe_w2, PE);
    add_pe0_kernel<<<ROWS0, 256, 0, stream>>>(scale0, PE, out);
    pool_kernel<<<ROWS1, 256, 0, stream>>>(out, scale1, PE + 65536, o1sec);

    sattn(o1sec, ROWS1, 16, 1);
    for (int c = 0; c < NC; c++)
        sattn(out + (size_t)c * R * 256, R, CW, 0);

    gather_g_kernel<<<4096, 256, 0, stream>>>(o1sec, G);
    ln16_kernel<<<4096, 256, 0, stream>>>(G, ln1_g + 256, ln1_b + 256, bufH16);
    hgemm(bufH16, wqkvT + 196608, bqkv + 768, nullptr, Q16, 4096, 256, 256, 0);
    for (int c = 0; c < NC; c++) {
        float* xch = out + (size_t)c * R * 256;
        ln16_kernel<<<R, 256, 0, stream>>>(xch, ln1_g + 256, ln1_b + 256, bufH16);
        hgemm(bufH16, wqkvT + 196608 + 65536, bqkv + 768 + 256, nullptr, qkv16, R, 512, 256, 0);
        cross_attn_kernel<<<CW * 16, 128, 0, stream>>>(Q16, qkv16, OX16, c * CW);
    }
    hgemm(OX16, woT + 65536, bo + 256, G, G, 4096, 256, 256, 0);
    ln16_kernel<<<4096, 256, 0, stream>>>(G, ln2_g + 256, ln2_b + 256, bufH16);
    hgemm(bufH16, mw1T + 262144, mb1 + 1024, nullptr, hid16, 4096, 1024, 256, 1);
    hgemm(hid16, mw2T + 262144, mb2 + 256, G, G, 4096, 256, 1024, 0);
    scatter_g_kernel<<<4096, 256, 0, stream>>>(G, o1sec);
}